// Round 9
// baseline (662.910 us; speedup 1.0000x reference)
//
#include <hip/hip_runtime.h>
#include <hip/hip_cooperative_groups.h>
#include <math.h>

namespace cg = cooperative_groups;

// ---------------------------------------------------------------------------
// NetVLAD on gfx950.
// conv1/conv2: implicit GEMM, v_mfma_f32_16x16x32_bf16, 128x128 tile, BK=64,
//   2 blocks/CU — FROZEN at the round-3-measured structure (~77-78 us x2):
//   W double-buffer, TWO barriers per step, counted vmcnt(4), W(s+2) in
//   flight across barriers, halo(cc+1) FIFO-first at tap==8, T5 setprio.
// tail_coop: ONE cooperative launch replaces post_conv+vlad+intra+finalize.
//   P1 assign(256 blk) + expand(256 blk grid-strided) -> sync ->
//   P2 vlad(256 blk) -> sync -> P3 intra (wave/row) -> sync -> P4 finalize.
//   Round-8 bug: P4 bound was 1048576 (2x the 524,288-elem vlad output) —
//   overran into xenc with garbage vraw reads. Output 0 PASSED in round 8,
//   proving coop launch + grid.sync + P1-P3 correct. Fixed bound only.
// Fragment layouts (HW-verified): A/B: idx=lane&15, k=(lane>>4)*8+j;
// C/D: col=lane&15 (B idx), row=(lane>>4)*4+reg (A idx).
// ---------------------------------------------------------------------------

typedef __bf16 bf16x8 __attribute__((ext_vector_type(8)));
typedef float f32x4 __attribute__((ext_vector_type(4)));

#define GLDS16(gp, lp)                                                  \
  __builtin_amdgcn_global_load_lds(                                     \
      (const __attribute__((address_space(1))) void*)(gp),              \
      (__attribute__((address_space(3))) void*)(lp), 16, 0, 0)

// ---------------- conv as implicit GEMM, halo-tiled, BK=64 -----------------
// grid (128 pixel-tiles, 4 o-tiles), block 256 = 4 waves (2x2)
// MODE 0: BN+ReLU -> padded NHWC bf16 (hpad).
// MODE 1: xebT bf16 [n][pix][512] (c-contiguous), no BN.
template <int MODE>
__global__ __launch_bounds__(256) void conv_gemm(
    const __bf16* __restrict__ in,  // padded NHWC bf16 [16][34][34][512]
    const __bf16* __restrict__ wt,  // prepacked+swizzled [512][72*64]
    const float* __restrict__ scale, const float* __restrict__ shift,
    __bf16* __restrict__ outp) {
  __shared__ __align__(16) __bf16 Hl[6 * 42 * 64];   // 16128 elem, 31.5 KB
  __shared__ __align__(16) __bf16 Wl[2 * 128 * 64];  // 32 KB (double-buffered)

  const int t = threadIdx.x;
  const int bx = blockIdx.x, oT = blockIdx.y;
  const int lane = t & 63, wid = t >> 6;
  const int l16 = lane & 15, q = lane >> 4;
  const int wrow = wid >> 1, wcol = wid & 1;

  const int n = bx >> 3;
  const int trow0 = (bx & 7) * 4;  // first pixel row of this 128-pixel tile

  // ---- W staging: 4 chunks/thread; Wl[buf][row][phys8] = row*64 + phys*8
  const int swr = t >> 3, sp = t & 7;
  const __bf16* wsrc[4];
#pragma unroll
  for (int i = 0; i < 4; ++i)
    wsrc[i] = wt + (size_t)(oT * 128 + 32 * i + swr) * 4608 + sp * 8;

  // ---- halo staging: 8 chunks/thread over 6 rows x 42 cols x 8 c8-chunks
  const __bf16* inb = in + (size_t)n * (1156 * 512);
  const __bf16* hsrc[8];
  bool hval[8];
#pragma unroll
  for (int i = 0; i < 8; ++i) {
    const int jj = t + 256 * i;
    hval[i] = jj < 2016;
    const int hr = jj / 336;
    const int hrem = jj - hr * 336;
    const int hw = hrem >> 3, hc8 = hrem & 7;
    hsrc[i] = inb + ((size_t)((trow0 + hr) * 34 + hw)) * 512 +
              (hc8 ^ (hw & 7)) * 8;
  }

  // ---- fragment read constants
  const int c0 = (q ^ (l16 & 7)) * 8;
  const int c1 = ((4 + q) ^ (l16 & 7)) * 8;
  int aoff[4], prow_[4], pcol_[4];
#pragma unroll
  for (int i = 0; i < 4; ++i) {
    aoff[i] = (wrow * 64 + i * 16 + l16) * 64;
    const int p = wcol * 64 + i * 16 + l16;
    prow_[i] = p >> 5;
    pcol_[i] = p & 31;
  }

  f32x4 acc[4][4];
#pragma unroll
  for (int i = 0; i < 4; ++i)
#pragma unroll
    for (int j = 0; j < 4; ++j) acc[i][j] = (f32x4){0.f, 0.f, 0.f, 0.f};

  // ---- prologue: halo(cc=0), W(step0)->Wl[0], W(step1)->Wl[1] ------------
  // step s has (cc,tap) = (s/9, s%9); woffs = (tap*8+cc)*64.
#pragma unroll
  for (int i = 0; i < 8; ++i)
    if (hval[i]) GLDS16(hsrc[i], Hl + (t + 256 * i) * 8);
#pragma unroll
  for (int i = 0; i < 4; ++i)
    GLDS16(wsrc[i], Wl + (t + 256 * i) * 8);  // step0: woffs=0
#pragma unroll
  for (int i = 0; i < 4; ++i)
    GLDS16(wsrc[i] + 512, Wl + 8192 + (t + 256 * i) * 8);  // step1: woffs=512
  // outstanding: halo(8) + W0(4) + W1(4). Wait halo+W0; keep W1 in flight.
  asm volatile("s_waitcnt vmcnt(4)" ::: "memory");
  __builtin_amdgcn_s_barrier();

  int tap = 0, dh = 0, dw = 0, cc = 0;  // step s
  int tap2 = 2, cc2 = 0;                // step s+2 (prefetch target)

#pragma unroll 1
  for (int s = 0; s < 72; ++s) {
    const int buf = (s & 1) << 13;  // 0 or 8192 elements
    const __bf16* Wb = Wl + buf;

    // A: fragment reads for step s
    bf16x8 aw[4][2], bp[4][2];
#pragma unroll
    for (int i = 0; i < 4; ++i) {
      aw[i][0] = *(const bf16x8*)&Wb[aoff[i] + c0];
      aw[i][1] = *(const bf16x8*)&Wb[aoff[i] + c1];
    }
#pragma unroll
    for (int i = 0; i < 4; ++i) {
      const int col = pcol_[i] + dw;
      const int rb = (prow_[i] + dh) * 2688 + col * 64;
      const int xr = col & 7;
      bp[i][0] = *(const bf16x8*)&Hl[rb + (q ^ xr) * 8];
      bp[i][1] = *(const bf16x8*)&Hl[rb + ((4 + q) ^ xr) * 8];
    }
    // B/C: reads landed in regs (cross-wave WAR vs incoming DMA), then sync.
    asm volatile("s_waitcnt lgkmcnt(0)" ::: "memory");
    __builtin_amdgcn_sched_barrier(0);
    __builtin_amdgcn_s_barrier();

    // D: issue next-halo FIRST (FIFO: so vmcnt(4) below covers it), then
    //    W(s+2) into the buffer step s just finished reading.
    if (tap == 8 && cc < 7) {
#pragma unroll
      for (int i = 0; i < 8; ++i)
        if (hval[i]) GLDS16(hsrc[i] + (cc + 1) * 64, Hl + (t + 256 * i) * 8);
    }
    if (s < 70) {
      const int woffs2 = (tap2 * 8 + cc2) * 64;
#pragma unroll
      for (int i = 0; i < 4; ++i)
        GLDS16(wsrc[i] + woffs2, Wl + buf + (t + 256 * i) * 8);
    }

    // E: MFMA cluster (T5)
    __builtin_amdgcn_s_setprio(1);
#pragma unroll
    for (int kh = 0; kh < 2; ++kh)
#pragma unroll
      for (int mt = 0; mt < 4; ++mt)
#pragma unroll
        for (int nt = 0; nt < 4; ++nt)
          acc[mt][nt] = __builtin_amdgcn_mfma_f32_16x16x32_bf16(
              aw[mt][kh], bp[nt][kh], acc[mt][nt], 0, 0, 0);
    __builtin_amdgcn_s_setprio(0);

    // F/G: counted wait — drain {W(s+1), halo-if-issued}; W(s+2) stays in
    // flight across the barrier. Tail drains fully.
    if (s < 70)
      asm volatile("s_waitcnt vmcnt(4)" ::: "memory");
    else
      asm volatile("s_waitcnt vmcnt(0)" ::: "memory");
    __builtin_amdgcn_s_barrier();

    // advance step / prefetch counters
    ++tap;
    ++dw;
    if (dw == 3) {
      dw = 0;
      ++dh;
    }
    if (tap == 9) {
      tap = 0;
      dh = 0;
      dw = 0;
      ++cc;
    }
    if (++tap2 == 9) {
      tap2 = 0;
      ++cc2;
    }
  }

  // ---- epilogue ----
#pragma unroll
  for (int nt = 0; nt < 4; ++nt) {
    const int m_l = wcol * 64 + nt * 16 + l16;
    const int mg2 = bx * 128 + m_l;
    const int n2 = mg2 >> 10, pix2 = mg2 & 1023;
#pragma unroll
    for (int mt = 0; mt < 4; ++mt) {
      const int ob = oT * 128 + wrow * 64 + mt * 16 + q * 4;
      f32x4 v = acc[mt][nt];
      union {
        __bf16 b[4];
        uint2 u;
      } pk;
      if (MODE == 0) {
        const f32x4 sc = *(const f32x4*)&scale[ob];
        const f32x4 sh = *(const f32x4*)&shift[ob];
#pragma unroll
        for (int r = 0; r < 4; ++r)
          pk.b[r] = (__bf16)fmaxf(v[r] * sc[r] + sh[r], 0.f);
        __bf16* dst = outp +
                      ((size_t)n2 * 1156 + ((pix2 >> 5) + 1) * 34 +
                       ((pix2 & 31) + 1)) * 512 + ob;
        *(uint2*)dst = pk.u;
      } else {
#pragma unroll
        for (int r = 0; r < 4; ++r) pk.b[r] = (__bf16)v[r];
        __bf16* dst = outp + ((size_t)n2 * 1024 + pix2) * 512 + ob;
        *(uint2*)dst = pk.u;
      }
    }
  }
}

// ---------------- cooperative tail: assign+expand | vlad | intra | final ---
// grid 512 x 256. LDS 48 KB -> 3 blocks/CU capacity (768) > 512: co-resident.
__global__ __launch_bounds__(256, 3) void tail_coop(
    const __bf16* __restrict__ xebT, const __bf16* __restrict__ watb,
    __bf16* __restrict__ saPb, float* __restrict__ S,
    float* __restrict__ xenc, __bf16* __restrict__ xeb,
    float* __restrict__ vpart, const float* __restrict__ cent,
    float* __restrict__ vraw, float* __restrict__ gss,
    float* __restrict__ out) {
  __shared__ __align__(16) char SMEM[49152];
  const int t = threadIdx.x;
  const int bx = blockIdx.x;
  const int lane = t & 63, wid = t >> 6;
  const int l16 = lane & 15, q = lane >> 4;
  cg::grid_group grid = cg::this_grid();

  // ================= P1: assign_softmax (bx<256) + expand (bx>=256) =======
  if (bx < 256) {
    __bf16* Al = (__bf16*)SMEM;             // [4][2048]
    __bf16* Wlb = (__bf16*)(SMEM + 16384);  // [4][2048]
    float* Sl = (float*)(SMEM + 32768);     // [64]
    const int pt = bx & 15, n = bx >> 4;
    if (t < 64) Sl[t] = 0.f;

    const int arow = t >> 2;  // pixel row 0..63
    const __bf16* asrc = xebT + ((size_t)n * 1024 + pt * 64 + arow) * 512 +
                         ((t & 3) ^ ((arow >> 1) & 3)) * 8;
    const __bf16* wsrc = watb + (size_t)(t >> 2) * 512 + (t & 3) * 8;
    const int ldsb = wid * 512;
    const int sw = (q ^ ((l16 >> 1) & 3)) * 8;
    const int pnoff = (t >> 2) * 32 + (t & 3) * 8;

    f32x4 acc[4];
#pragma unroll
    for (int i = 0; i < 4; ++i) acc[i] = (f32x4){0.f, 0.f, 0.f, 0.f};
    float pn = 0.f;

#pragma unroll
    for (int p = 0; p < 3; ++p) {
      GLDS16(asrc + p * 32, Al + p * 2048 + ldsb);
      GLDS16(wsrc + p * 32, Wlb + p * 2048 + ldsb);
    }
    asm volatile("s_waitcnt vmcnt(4)" ::: "memory");
    __builtin_amdgcn_s_barrier();

#pragma unroll 1
    for (int kc = 0; kc < 16; ++kc) {
      const __bf16* Ab = Al + (kc & 3) * 2048;
      const __bf16* Wb = Wlb + (kc & 3) * 2048;
      bf16x8 pv = *(const bf16x8*)&Ab[pnoff];
      bf16x8 pf = *(const bf16x8*)&Ab[(wid * 16 + l16) * 32 + sw];
      bf16x8 wf[4];
#pragma unroll
      for (int ka = 0; ka < 4; ++ka)
        wf[ka] = *(const bf16x8*)&Wb[(ka * 16 + l16) * 32 + sw];
      asm volatile("s_waitcnt lgkmcnt(0)" ::: "memory");
      __builtin_amdgcn_sched_barrier(0);
      __builtin_amdgcn_s_barrier();
      if (kc + 3 < 16) {
        GLDS16(asrc + (kc + 3) * 32, Al + ((kc + 3) & 3) * 2048 + ldsb);
        GLDS16(wsrc + (kc + 3) * 32, Wlb + ((kc + 3) & 3) * 2048 + ldsb);
      }
#pragma unroll
      for (int j = 0; j < 8; ++j) {
        float f = (float)pv[j];
        pn = fmaf(f, f, pn);
      }
#pragma unroll
      for (int ka = 0; ka < 4; ++ka)
        acc[ka] = __builtin_amdgcn_mfma_f32_16x16x32_bf16(wf[ka], pf, acc[ka],
                                                          0, 0, 0);
      if (kc < 13)
        asm volatile("s_waitcnt vmcnt(4)" ::: "memory");
      else
        asm volatile("s_waitcnt vmcnt(0)" ::: "memory");
      __builtin_amdgcn_s_barrier();
    }
    pn += __shfl_xor(pn, 1);
    pn += __shfl_xor(pn, 2);
    const float rn = 1.0f / fmaxf(sqrtf(__shfl(pn, l16 * 4)), 1e-12f);

    float sc[16];
    float m = -3.4e38f;
#pragma unroll
    for (int ka = 0; ka < 4; ++ka)
#pragma unroll
      for (int r = 0; r < 4; ++r) {
        float v = acc[ka][r] * rn;
        sc[ka * 4 + r] = v;
        m = fmaxf(m, v);
      }
    m = fmaxf(m, __shfl_xor(m, 16));
    m = fmaxf(m, __shfl_xor(m, 32));
    float s = 0.f;
#pragma unroll
    for (int j = 0; j < 16; ++j) {
      sc[j] = __expf(sc[j] - m);
      s += sc[j];
    }
    s += __shfl_xor(s, 16);
    s += __shfl_xor(s, 32);
    const float inv = 1.0f / s;
    const int pixg = pt * 64 + wid * 16 + l16;
#pragma unroll
    for (int j = 0; j < 16; ++j) {
      const int k = (j >> 2) * 16 + q * 4 + (j & 3);
      float sa = sc[j] * inv;
      sc[j] = sa;
      saPb[((size_t)n * 64 + k) * 1024 + pixg] = (__bf16)(sa * rn);
    }
#pragma unroll
    for (int j = 0; j < 16; ++j) {
      float v = sc[j];
      v += __shfl_xor(v, 1);
      v += __shfl_xor(v, 2);
      v += __shfl_xor(v, 4);
      v += __shfl_xor(v, 8);
      sc[j] = v;
    }
    if (l16 == 0) {
#pragma unroll
      for (int j = 0; j < 16; ++j)
        atomicAdd(&Sl[(j >> 2) * 16 + q * 4 + (j & 3)], sc[j]);
    }
    __syncthreads();
    if (t < 64) atomicAdd(&S[n * 64 + t], Sl[t]);
  } else {
    // expand: 256 blocks grid-stride over 2048 tiles (8 each)
    __bf16* Ll = (__bf16*)SMEM;  // 8 KB carve
#pragma unroll 1
    for (int e = bx - 256; e < 2048; e += 256) {
      const int cc = e & 7, ptile = (e >> 3) & 15, n = e >> 7;
      const int p0 = ptile * 64, c0 = cc * 64;
#pragma unroll
      for (int i = 0; i < 2; ++i) {
        const int u = t * 2 + i;
        const int pix = u >> 3, c8 = u & 7;
        uint4 v = *(const uint4*)&xebT[((size_t)n * 1024 + p0 + pix) * 512 +
                                       c0 + c8 * 8];
        *(uint4*)&Ll[pix * 64 + (c8 ^ (pix & 7)) * 8] = v;
      }
      __syncthreads();
      const int c = t >> 2, g = t & 3;
      union {
        float f[4];
        float4 v;
      } fv[4];
      union {
        __bf16 b[16];
        uint4 u[2];
      } bv;
#pragma unroll
      for (int r = 0; r < 16; ++r) {
        const int pix = g * 16 + r;
        __bf16 b = Ll[pix * 64 + ((c >> 3) ^ (pix & 7)) * 8 + (c & 7)];
        bv.b[r] = b;
        fv[r >> 2].f[r & 3] = (float)b;
      }
      float* fd = xenc + ((size_t)n * 512 + c0 + c) * 1024 + p0 + g * 16;
#pragma unroll
      for (int r = 0; r < 4; ++r) *(float4*)(fd + r * 4) = fv[r].v;
      __bf16* bd = xeb + ((size_t)n * 512 + c0 + c) * 1024 + p0 + g * 16;
      *(uint4*)bd = bv.u[0];
      *(uint4*)(bd + 8) = bv.u[1];
      __syncthreads();  // LDS WAR before next tile's stage
    }
  }

  __threadfence();
  grid.sync();

  // ================= P2: vlad GEMM (bx<256) ================================
  if (bx < 256) {
    __bf16* Av = (__bf16*)SMEM;            // [4][2048]
    __bf16* Bv = (__bf16*)(SMEM + 16384);  // [4][4096]
    const int cT = bx & 3, n = (bx >> 2) & 15, ks = bx >> 6;
    const int wrow = wid >> 1, wcol = wid & 1;

    const int ar = t >> 2, acp = t & 3;
    const __bf16* asrc = saPb + (size_t)n * 65536 + (size_t)ar * 1024 +
                         ks * 256 + (acp ^ ((ar >> 1) & 3)) * 8;
    const int br0 = t >> 2, bcp0 = t & 3;
    const int br1 = (t + 256) >> 2, bcp1 = t & 3;
    const __bf16* bsrc0 = xeb + (size_t)n * 524288 +
                          (size_t)(cT * 128 + br0) * 1024 + ks * 256 +
                          (bcp0 ^ ((br0 >> 1) & 3)) * 8;
    const __bf16* bsrc1 = xeb + (size_t)n * 524288 +
                          (size_t)(cT * 128 + br1) * 1024 + ks * 256 +
                          (bcp1 ^ ((br1 >> 1) & 3)) * 8;

    const int ldsb = wid * 512;
    const int sw = (q ^ ((l16 >> 1) & 3)) * 8;

    f32x4 acc[2][4];
#pragma unroll
    for (int i = 0; i < 2; ++i)
#pragma unroll
      for (int j = 0; j < 4; ++j) acc[i][j] = (f32x4){0.f, 0.f, 0.f, 0.f};

#pragma unroll
    for (int p = 0; p < 3; ++p) {
      GLDS16(asrc + p * 32, Av + p * 2048 + ldsb);
      GLDS16(bsrc0 + p * 32, Bv + p * 4096 + ldsb);
      GLDS16(bsrc1 + p * 32, Bv + p * 4096 + 2048 + ldsb);
    }
    asm volatile("s_waitcnt vmcnt(6)" ::: "memory");
    __builtin_amdgcn_s_barrier();

#pragma unroll 1
    for (int kc = 0; kc < 8; ++kc) {
      const __bf16* Ab = Av + (kc & 3) * 2048;
      const __bf16* Bb = Bv + (kc & 3) * 4096;
      bf16x8 af[2], bf[4];
#pragma unroll
      for (int i = 0; i < 2; ++i)
        af[i] = *(const bf16x8*)&Ab[(wrow * 32 + i * 16 + l16) * 32 + sw];
#pragma unroll
      for (int i = 0; i < 4; ++i)
        bf[i] = *(const bf16x8*)&Bb[(wcol * 64 + i * 16 + l16) * 32 + sw];
      asm volatile("s_waitcnt lgkmcnt(0)" ::: "memory");
      __builtin_amdgcn_sched_barrier(0);
      __builtin_amdgcn_s_barrier();
      if (kc + 3 < 8) {
        GLDS16(asrc + (kc + 3) * 32, Av + ((kc + 3) & 3) * 2048 + ldsb);
        GLDS16(bsrc0 + (kc + 3) * 32, Bv + ((kc + 3) & 3) * 4096 + ldsb);
        GLDS16(bsrc1 + (kc + 3) * 32,
               Bv + ((kc + 3) & 3) * 4096 + 2048 + ldsb);
      }
#pragma unroll
      for (int mt = 0; mt < 2; ++mt)
#pragma unroll
        for (int nt = 0; nt < 4; ++nt)
          acc[mt][nt] = __builtin_amdgcn_mfma_f32_16x16x32_bf16(
              af[mt], bf[nt], acc[mt][nt], 0, 0, 0);
      if (kc < 5)
        asm volatile("s_waitcnt vmcnt(6)" ::: "memory");
      else
        asm volatile("s_waitcnt vmcnt(0)" ::: "memory");
      __builtin_amdgcn_s_barrier();
    }

    float* vp = vpart + (size_t)(ks * 16 + n) * 32768;
#pragma unroll
    for (int mt = 0; mt < 2; ++mt) {
      const int krow = wrow * 32 + mt * 16 + q * 4;
#pragma unroll
      for (int nt = 0; nt < 4; ++nt) {
        const int ccol = cT * 128 + wcol * 64 + nt * 16 + l16;
#pragma unroll
        for (int r = 0; r < 4; ++r)
          vp[(size_t)(krow + r) * 512 + ccol] = acc[mt][nt][r];
      }
    }
  }

  __threadfence();
  grid.sync();

  // ================= P3: intra-norm — one wave per (n,k) row ==============
  {
    const int b = bx * 4 + wid;  // row id; active < 1024
    if (b < 1024) {
      const int n = b >> 6, k = b & 63;
      const float s = S[b];
      float v[8];
      float ss = 0.f;
#pragma unroll
      for (int j = 0; j < 8; ++j) {
        const int c = lane * 8 + j;
        const size_t off = (size_t)b * 512 + c;
        float val = vpart[off] + vpart[524288 + off] +
                    vpart[2 * 524288 + off] + vpart[3 * 524288 + off] -
                    s * cent[k * 512 + c];
        v[j] = val;
        ss += val * val;
      }
#pragma unroll
      for (int off = 1; off < 64; off <<= 1) ss += __shfl_xor(ss, off);
      const float rn = 1.0f / fmaxf(sqrtf(ss), 1e-12f);
#pragma unroll
      for (int j = 0; j < 8; ++j)
        vraw[(size_t)b * 512 + lane * 8 + j] = v[j] * rn;
      if (lane == 0) atomicAdd(&gss[n], ss * rn * rn);
    }
  }

  __threadfence();
  grid.sync();

  // ================= P4: finalize (grid-strided, 524288 elems) ============
#pragma unroll 1
  for (int id = bx * 256 + t; id < 524288; id += 512 * 256) {
    const int n = id >> 15;
    out[id] = vraw[id] * (1.0f / fmaxf(sqrtf(gss[n]), 1e-12f));
  }
}

// ---------------- fused prep: zero_border + misc + xform + wt_prep ---------
// grid layout: [0,1056) zero-border, [1056,1191) misc, [1191,1703) xform,
// [1703,2727) wt_prep. All independent writes; fusing overlaps them across
// CUs and drops 3 launch gaps.
__global__ __launch_bounds__(256) void prep_all(
    const float* __restrict__ x, const float* __restrict__ w1,
    const float* __restrict__ w2, const float* __restrict__ g,
    const float* __restrict__ b, const float* __restrict__ m,
    const float* __restrict__ v, const float* __restrict__ wA,
    __bf16* __restrict__ xpad, __bf16* __restrict__ hpad,
    __bf16* __restrict__ wt1, __bf16* __restrict__ wt2,
    float* __restrict__ scale, float* __restrict__ shift,
    __bf16* __restrict__ watb, float* __restrict__ Sz) {
  __shared__ float Lw[4608];
  const int bx = blockIdx.x;
  const int t = threadIdx.x;

  if (bx < 1056) {
    // ---- zero the 132-pixel pad ring of xpad/hpad ----
    const int which = bx >= 528;
    const int id = (which ? bx - 528 : bx) * 256 + t;  // 0..135167
    const int n = id / 8448;
    const int rem = id - n * 8448;
    const int pb = rem >> 6;  // 0..131 border pixel
    const int c8 = rem & 63;
    int h, w;
    if (pb < 34) {
      h = 0;
      w = pb;
    } else if (pb < 68) {
      h = 33;
      w = pb - 34;
    } else {
      const int r2 = pb - 68;
      h = 1 + (r2 >> 1);
      w = (r2 & 1) * 33;
    }
    __bf16* base = which ? hpad : xpad;
    *(uint4*)(base + ((size_t)n * 1156 + h * 34 + w) * 512 + c8 * 8) =
        (uint4){0u, 0u, 0u, 0u};
  } else if (bx < 1191) {
    // ---- misc: BN fold, watb swizzle, S zero ----
    const int i = (bx - 1056) * 256 + t;
    if (i < 512) {
      float sc = g[i] / sqrtf(v[i] + 1e-5f);
      scale[i] = sc;
      shift[i] = b[i] - m[i] * sc;
    } else if (i < 512 + 32768) {
      const int id = i - 512;
      const int k = id >> 9, j = id & 511;
      const int kt = j >> 5, cpos = (j >> 3) & 3, e = j & 7;
      const int c = kt * 32 + (cpos ^ ((k >> 1) & 3)) * 8 + e;
      watb[(size_t)k * 512 + j] = (__bf16)wA[(size_t)k * 512 + c];
    } else if (i < 512 + 32768 + 1040) {
      Sz[i - (512 + 32768)] = 0.f;
    }
  } else if (bx < 1703) {
    // ---- xform: x (fp32 NCHW) -> xpad (bf16 NHWC padded) ----
    const int bb = bx - 1191;
    const int n = bb >> 5, h = bb & 31;
    const int w = t & 31, cg = t >> 5;
    const float* src = x + ((size_t)n * 512 + cg * 64) * 1024 + h * 32 + w;
    __bf16* dst =
        xpad + ((size_t)n * 1156 + (h + 1) * 34 + (w + 1)) * 512 + cg * 64;
    float fv[64];
#pragma unroll
    for (int j = 0; j < 64; ++j) fv[j] = src[j * 1024];  // all loads in flight
#pragma unroll
    for (int jj = 0; jj < 8; ++jj) {
      union {
        __bf16 b8[8];
        uint4 u;
      } pk;
#pragma unroll
      for (int j = 0; j < 8; ++j) pk.b8[j] = (__bf16)fv[jj * 8 + j];
      *(uint4*)(dst + jj * 8) = pk.u;
    }
  } else {
    // ---- wt_prep: OIHW fp32 -> [o][kt*64 + p*8 + e] bf16, swizzle baked ---
    const int bb = bx - 1703;  // 0..1023
    const int o = bb & 511;
    const float* w = (bb >> 9) ? w2 : w1;
    __bf16* wt = (bb >> 9) ? wt2 : wt1;
#pragma unroll
    for (int i = 0; i < 18; ++i)
      Lw[t + 256 * i] = w[(size_t)o * 4608 + t + 256 * i];
    __syncthreads();
#pragma unroll
    for (int i = 0; i < 18; ++i) {
      const int idk = t + 256 * i;
      const int kt = idk >> 6;
      const int p = (idk >> 3) & 7, e = idk & 7;
      const int logical = p ^ (o & 7);
      const int k2 = kt * 64 + logical * 8 + e;
      const int tap = k2 >> 9, ci = k2 & 511;
      wt[(size_t)o * 4608 + idk] = (__bf16)Lw[ci * 9 + tap];
    }
  }
}

// ---------------------------------------------------------------------------
extern "C" void kernel_launch(void* const* d_in, const int* in_sizes, int n_in,
                              void* d_out, int out_size, void* d_ws,
                              size_t ws_size, hipStream_t stream) {
  const float* x = (const float*)d_in[0];
  const float* w1 = (const float*)d_in[1];
  const float* gam = (const float*)d_in[2];
  const float* bet = (const float*)d_in[3];
  const float* mean = (const float*)d_in[4];
  const float* var = (const float*)d_in[5];
  const float* w2 = (const float*)d_in[6];
  const float* wA = (const float*)d_in[7];
  const float* cent = (const float*)d_in[8];
  float* out = (float*)d_out;

  char* ws = (char*)d_ws;
  __bf16* Wt1 = (__bf16*)(ws + 0);          // 4,718,592 (dead after conv1)
  __bf16* Wt2 = (__bf16*)(ws + 4718592);    // 4,718,592 (dead after conv2)
  __bf16* xpad = (__bf16*)(ws + 9437184);   // 18,939,904 (dead after conv1)
  __bf16* xebT = (__bf16*)(ws + 9437184);   // alias: 16,777,216 (conv2 out)
  __bf16* saPb = (__bf16*)(ws + 26214400);  // 2,097,152
  __bf16* hpad = (__bf16*)(ws + 28377088);  // 18,939,904 (dead after conv2)
  __bf16* xeb = (__bf16*)(ws + 28377088);   // alias: 16,777,216 (expand out)
  float* vpart = (float*)(ws + 0);          // alias Wt1/2: 8,388,608
  float* vraw = (float*)(ws + 8388608);     // alias: 2,097,152
  float* scale = (float*)(ws + 47316992);   // 2048 B
  float* shift = (float*)(ws + 47319040);   // 2048 B
  __bf16* watb = (__bf16*)(ws + 47321088);  // 65,536 B
  float* S = (float*)(ws + 47386624);       // 4096 B
  float* gss = (float*)(ws + 47390720);     // 64 B

  float* xenc = out + 524288;  // output 1 (x_enc, fp32 NCHW)

  prep_all<<<2727, 256, 0, stream>>>(x, w1, w2, gam, bet, mean, var, wA, xpad,
                                     hpad, Wt1, Wt2, scale, shift, watb, S);

  conv_gemm<0><<<dim3(128, 4), 256, 0, stream>>>(xpad, Wt1, scale, shift, hpad);
  conv_gemm<1><<<dim3(128, 4), 256, 0, stream>>>(hpad, Wt2, nullptr, nullptr,
                                                 xebT);

  void* args[] = {&xebT, &watb, &saPb, &S,    &xenc, &xeb,
                  &vpart, &cent, &vraw, &gss, &out};
  hipLaunchCooperativeKernel((void*)tail_coop, dim3(512), dim3(256), args, 0,
                             stream);
}

// Round 10
// 302.904 us; speedup vs baseline: 2.1885x; 2.1885x over previous
//
#include <hip/hip_runtime.h>
#include <math.h>

// ---------------------------------------------------------------------------
// NetVLAD on gfx950.  (REVERT to round-7 structure — measured best 307.0 us.)
// conv1/conv2: implicit GEMM, v_mfma_f32_16x16x32_bf16, 128x128 tile, BK=64,
//   2 blocks/CU — FROZEN: W double-buffer, TWO barriers per step, counted
//   vmcnt(4), W(s+2) in flight across barriers, halo(cc+1) FIFO-first at
//   tap==8, T5 setprio.  (256x128 tile: -55%; W triple-buffer: -17%;
//   coop-fused tail: grid.sync spin cost ~100us/sync on gfx950 -> tail
//   415us vs ~150us as separate kernels. All measured, all reverted.)
// post_conv: fused assign_softmax (256 blocks, first) + expand_x (2048).
// vlad: 4-deep LDS multibuffer, counted vmcnt. prep_all: fused prep.
// Fragment layouts (HW-verified): A/B: idx=lane&15, k=(lane>>4)*8+j;
// C/D: col=lane&15 (B idx), row=(lane>>4)*4+reg (A idx).
// ---------------------------------------------------------------------------

typedef __bf16 bf16x8 __attribute__((ext_vector_type(8)));
typedef float f32x4 __attribute__((ext_vector_type(4)));

#define GLDS16(gp, lp)                                                  \
  __builtin_amdgcn_global_load_lds(                                     \
      (const __attribute__((address_space(1))) void*)(gp),              \
      (__attribute__((address_space(3))) void*)(lp), 16, 0, 0)

// ---------------- conv as implicit GEMM, halo-tiled, BK=64 -----------------
// grid (128 pixel-tiles, 4 o-tiles), block 256 = 4 waves (2x2)
// MODE 0: BN+ReLU -> padded NHWC bf16 (hpad).
// MODE 1: xebT bf16 [n][pix][512] (c-contiguous), no BN.
template <int MODE>
__global__ __launch_bounds__(256) void conv_gemm(
    const __bf16* __restrict__ in,  // padded NHWC bf16 [16][34][34][512]
    const __bf16* __restrict__ wt,  // prepacked+swizzled [512][72*64]
    const float* __restrict__ scale, const float* __restrict__ shift,
    __bf16* __restrict__ outp) {
  __shared__ __align__(16) __bf16 Hl[6 * 42 * 64];   // 16128 elem, 31.5 KB
  __shared__ __align__(16) __bf16 Wl[2 * 128 * 64];  // 32 KB (double-buffered)

  const int t = threadIdx.x;
  const int bx = blockIdx.x, oT = blockIdx.y;
  const int lane = t & 63, wid = t >> 6;
  const int l16 = lane & 15, q = lane >> 4;
  const int wrow = wid >> 1, wcol = wid & 1;

  const int n = bx >> 3;
  const int trow0 = (bx & 7) * 4;  // first pixel row of this 128-pixel tile

  // ---- W staging: 4 chunks/thread; Wl[buf][row][phys8] = row*64 + phys*8
  const int swr = t >> 3, sp = t & 7;
  const __bf16* wsrc[4];
#pragma unroll
  for (int i = 0; i < 4; ++i)
    wsrc[i] = wt + (size_t)(oT * 128 + 32 * i + swr) * 4608 + sp * 8;

  // ---- halo staging: 8 chunks/thread over 6 rows x 42 cols x 8 c8-chunks
  const __bf16* inb = in + (size_t)n * (1156 * 512);
  const __bf16* hsrc[8];
  bool hval[8];
#pragma unroll
  for (int i = 0; i < 8; ++i) {
    const int jj = t + 256 * i;
    hval[i] = jj < 2016;
    const int hr = jj / 336;
    const int hrem = jj - hr * 336;
    const int hw = hrem >> 3, hc8 = hrem & 7;
    hsrc[i] = inb + ((size_t)((trow0 + hr) * 34 + hw)) * 512 +
              (hc8 ^ (hw & 7)) * 8;
  }

  // ---- fragment read constants
  const int c0 = (q ^ (l16 & 7)) * 8;
  const int c1 = ((4 + q) ^ (l16 & 7)) * 8;
  int aoff[4], prow_[4], pcol_[4];
#pragma unroll
  for (int i = 0; i < 4; ++i) {
    aoff[i] = (wrow * 64 + i * 16 + l16) * 64;
    const int p = wcol * 64 + i * 16 + l16;
    prow_[i] = p >> 5;
    pcol_[i] = p & 31;
  }

  f32x4 acc[4][4];
#pragma unroll
  for (int i = 0; i < 4; ++i)
#pragma unroll
    for (int j = 0; j < 4; ++j) acc[i][j] = (f32x4){0.f, 0.f, 0.f, 0.f};

  // ---- prologue: halo(cc=0), W(step0)->Wl[0], W(step1)->Wl[1] ------------
  // step s has (cc,tap) = (s/9, s%9); woffs = (tap*8+cc)*64.
#pragma unroll
  for (int i = 0; i < 8; ++i)
    if (hval[i]) GLDS16(hsrc[i], Hl + (t + 256 * i) * 8);
#pragma unroll
  for (int i = 0; i < 4; ++i)
    GLDS16(wsrc[i], Wl + (t + 256 * i) * 8);  // step0: woffs=0
#pragma unroll
  for (int i = 0; i < 4; ++i)
    GLDS16(wsrc[i] + 512, Wl + 8192 + (t + 256 * i) * 8);  // step1: woffs=512
  // outstanding: halo(8) + W0(4) + W1(4). Wait halo+W0; keep W1 in flight.
  asm volatile("s_waitcnt vmcnt(4)" ::: "memory");
  __builtin_amdgcn_s_barrier();

  int tap = 0, dh = 0, dw = 0, cc = 0;  // step s
  int tap2 = 2, cc2 = 0;                // step s+2 (prefetch target)

#pragma unroll 1
  for (int s = 0; s < 72; ++s) {
    const int buf = (s & 1) << 13;  // 0 or 8192 elements
    const __bf16* Wb = Wl + buf;

    // A: fragment reads for step s
    bf16x8 aw[4][2], bp[4][2];
#pragma unroll
    for (int i = 0; i < 4; ++i) {
      aw[i][0] = *(const bf16x8*)&Wb[aoff[i] + c0];
      aw[i][1] = *(const bf16x8*)&Wb[aoff[i] + c1];
    }
#pragma unroll
    for (int i = 0; i < 4; ++i) {
      const int col = pcol_[i] + dw;
      const int rb = (prow_[i] + dh) * 2688 + col * 64;
      const int xr = col & 7;
      bp[i][0] = *(const bf16x8*)&Hl[rb + (q ^ xr) * 8];
      bp[i][1] = *(const bf16x8*)&Hl[rb + ((4 + q) ^ xr) * 8];
    }
    // B/C: reads landed in regs (cross-wave WAR vs incoming DMA), then sync.
    asm volatile("s_waitcnt lgkmcnt(0)" ::: "memory");
    __builtin_amdgcn_sched_barrier(0);
    __builtin_amdgcn_s_barrier();

    // D: issue next-halo FIRST (FIFO: so vmcnt(4) below covers it), then
    //    W(s+2) into the buffer step s just finished reading.
    if (tap == 8 && cc < 7) {
#pragma unroll
      for (int i = 0; i < 8; ++i)
        if (hval[i]) GLDS16(hsrc[i] + (cc + 1) * 64, Hl + (t + 256 * i) * 8);
    }
    if (s < 70) {
      const int woffs2 = (tap2 * 8 + cc2) * 64;
#pragma unroll
      for (int i = 0; i < 4; ++i)
        GLDS16(wsrc[i] + woffs2, Wl + buf + (t + 256 * i) * 8);
    }

    // E: MFMA cluster (T5)
    __builtin_amdgcn_s_setprio(1);
#pragma unroll
    for (int kh = 0; kh < 2; ++kh)
#pragma unroll
      for (int mt = 0; mt < 4; ++mt)
#pragma unroll
        for (int nt = 0; nt < 4; ++nt)
          acc[mt][nt] = __builtin_amdgcn_mfma_f32_16x16x32_bf16(
              aw[mt][kh], bp[nt][kh], acc[mt][nt], 0, 0, 0);
    __builtin_amdgcn_s_setprio(0);

    // F/G: counted wait — drain {W(s+1), halo-if-issued}; W(s+2) stays in
    // flight across the barrier. Tail drains fully.
    if (s < 70)
      asm volatile("s_waitcnt vmcnt(4)" ::: "memory");
    else
      asm volatile("s_waitcnt vmcnt(0)" ::: "memory");
    __builtin_amdgcn_s_barrier();

    // advance step / prefetch counters
    ++tap;
    ++dw;
    if (dw == 3) {
      dw = 0;
      ++dh;
    }
    if (tap == 9) {
      tap = 0;
      dh = 0;
      dw = 0;
      ++cc;
    }
    if (++tap2 == 9) {
      tap2 = 0;
      ++cc2;
    }
  }

  // ---- epilogue ----
#pragma unroll
  for (int nt = 0; nt < 4; ++nt) {
    const int m_l = wcol * 64 + nt * 16 + l16;
    const int mg2 = bx * 128 + m_l;
    const int n2 = mg2 >> 10, pix2 = mg2 & 1023;
#pragma unroll
    for (int mt = 0; mt < 4; ++mt) {
      const int ob = oT * 128 + wrow * 64 + mt * 16 + q * 4;
      f32x4 v = acc[mt][nt];
      union {
        __bf16 b[4];
        uint2 u;
      } pk;
      if (MODE == 0) {
        const f32x4 sc = *(const f32x4*)&scale[ob];
        const f32x4 sh = *(const f32x4*)&shift[ob];
#pragma unroll
        for (int r = 0; r < 4; ++r)
          pk.b[r] = (__bf16)fmaxf(v[r] * sc[r] + sh[r], 0.f);
        __bf16* dst = outp +
                      ((size_t)n2 * 1156 + ((pix2 >> 5) + 1) * 34 +
                       ((pix2 & 31) + 1)) * 512 + ob;
        *(uint2*)dst = pk.u;
      } else {
#pragma unroll
        for (int r = 0; r < 4; ++r) pk.b[r] = (__bf16)v[r];
        __bf16* dst = outp + ((size_t)n2 * 1024 + pix2) * 512 + ob;
        *(uint2*)dst = pk.u;
      }
    }
  }
}

// ---------------- fused post-conv2: assign_softmax + expand_x --------------
// bx < 256: assign_softmax (latency-bound long pole — dispatched first).
// bx >= 256: expand_x (BW-bound, fills remaining CUs).
__global__ __launch_bounds__(256) void post_conv(
    const __bf16* __restrict__ xebT, const __bf16* __restrict__ watb,
    __bf16* __restrict__ saPb, float* __restrict__ S,
    float* __restrict__ xenc, __bf16* __restrict__ xeb) {
  __shared__ __align__(16) __bf16 Al[4][64 * 32];
  __shared__ __align__(16) __bf16 Wlb[4][64 * 32];
  __shared__ float Sl[64];
  const int t = threadIdx.x;
  const int bx0 = blockIdx.x;

  if (bx0 < 256) {
    // ======== assign_softmax (4-deep pipeline) ========
    const int pt = bx0 & 15, n = bx0 >> 4;
    const int lane = t & 63, wid = t >> 6;
    const int l16 = lane & 15, q = lane >> 4;
    if (t < 64) Sl[t] = 0.f;

    const int arow = t >> 2;  // pixel row 0..63
    const __bf16* asrc = xebT + ((size_t)n * 1024 + pt * 64 + arow) * 512 +
                         ((t & 3) ^ ((arow >> 1) & 3)) * 8;
    const __bf16* wsrc = watb + (size_t)(t >> 2) * 512 + (t & 3) * 8;
    const int ldsb = wid * 512;
    const int sw = (q ^ ((l16 >> 1) & 3)) * 8;
    const int pnoff = (t >> 2) * 32 + (t & 3) * 8;

    f32x4 acc[4];
#pragma unroll
    for (int i = 0; i < 4; ++i) acc[i] = (f32x4){0.f, 0.f, 0.f, 0.f};
    float pn = 0.f;

#pragma unroll
    for (int p = 0; p < 3; ++p) {
      GLDS16(asrc + p * 32, (__bf16*)Al[p] + ldsb);
      GLDS16(wsrc + p * 32, (__bf16*)Wlb[p] + ldsb);
    }
    asm volatile("s_waitcnt vmcnt(4)" ::: "memory");
    __builtin_amdgcn_s_barrier();

#pragma unroll 1
    for (int kc = 0; kc < 16; ++kc) {
      const __bf16* Ab = Al[kc & 3];
      const __bf16* Wb = Wlb[kc & 3];
      bf16x8 pv = *(const bf16x8*)&Ab[pnoff];
      bf16x8 pf = *(const bf16x8*)&Ab[(wid * 16 + l16) * 32 + sw];
      bf16x8 wf[4];
#pragma unroll
      for (int ka = 0; ka < 4; ++ka)
        wf[ka] = *(const bf16x8*)&Wb[(ka * 16 + l16) * 32 + sw];
      asm volatile("s_waitcnt lgkmcnt(0)" ::: "memory");
      __builtin_amdgcn_sched_barrier(0);
      __builtin_amdgcn_s_barrier();
      if (kc + 3 < 16) {
        GLDS16(asrc + (kc + 3) * 32, (__bf16*)Al[(kc + 3) & 3] + ldsb);
        GLDS16(wsrc + (kc + 3) * 32, (__bf16*)Wlb[(kc + 3) & 3] + ldsb);
      }
#pragma unroll
      for (int j = 0; j < 8; ++j) {
        float f = (float)pv[j];
        pn = fmaf(f, f, pn);
      }
#pragma unroll
      for (int ka = 0; ka < 4; ++ka)
        acc[ka] = __builtin_amdgcn_mfma_f32_16x16x32_bf16(wf[ka], pf, acc[ka],
                                                          0, 0, 0);
      if (kc < 13)
        asm volatile("s_waitcnt vmcnt(4)" ::: "memory");
      else
        asm volatile("s_waitcnt vmcnt(0)" ::: "memory");
      __builtin_amdgcn_s_barrier();
    }
    pn += __shfl_xor(pn, 1);
    pn += __shfl_xor(pn, 2);
    const float rn = 1.0f / fmaxf(sqrtf(__shfl(pn, l16 * 4)), 1e-12f);

    float sc[16];
    float m = -3.4e38f;
#pragma unroll
    for (int ka = 0; ka < 4; ++ka)
#pragma unroll
      for (int r = 0; r < 4; ++r) {
        float v = acc[ka][r] * rn;
        sc[ka * 4 + r] = v;
        m = fmaxf(m, v);
      }
    m = fmaxf(m, __shfl_xor(m, 16));
    m = fmaxf(m, __shfl_xor(m, 32));
    float s = 0.f;
#pragma unroll
    for (int j = 0; j < 16; ++j) {
      sc[j] = __expf(sc[j] - m);
      s += sc[j];
    }
    s += __shfl_xor(s, 16);
    s += __shfl_xor(s, 32);
    const float inv = 1.0f / s;
    const int pixg = pt * 64 + wid * 16 + l16;
#pragma unroll
    for (int j = 0; j < 16; ++j) {
      const int k = (j >> 2) * 16 + q * 4 + (j & 3);
      float sa = sc[j] * inv;
      sc[j] = sa;
      saPb[((size_t)n * 64 + k) * 1024 + pixg] = (__bf16)(sa * rn);
    }
#pragma unroll
    for (int j = 0; j < 16; ++j) {
      float v = sc[j];
      v += __shfl_xor(v, 1);
      v += __shfl_xor(v, 2);
      v += __shfl_xor(v, 4);
      v += __shfl_xor(v, 8);
      sc[j] = v;
    }
    if (l16 == 0) {
#pragma unroll
      for (int j = 0; j < 16; ++j)
        atomicAdd(&Sl[(j >> 2) * 16 + q * 4 + (j & 3)], sc[j]);
    }
    __syncthreads();
    if (t < 64) atomicAdd(&S[n * 64 + t], Sl[t]);
  } else {
    // ======== expand_x: xebT [pix][c] -> xenc fp32 [c][pix] + xeb bf16 ====
    const int e = bx0 - 256;
    const int cc = e & 7, ptile = (e >> 3) & 15, n = e >> 7;
    __bf16* Ll = (__bf16*)Al;  // 8 KB carve
    const int p0 = ptile * 64, c0 = cc * 64;
#pragma unroll
    for (int i = 0; i < 2; ++i) {
      const int u = t * 2 + i;
      const int pix = u >> 3, c8 = u & 7;
      uint4 v = *(const uint4*)&xebT[((size_t)n * 1024 + p0 + pix) * 512 + c0 +
                                     c8 * 8];
      *(uint4*)&Ll[pix * 64 + (c8 ^ (pix & 7)) * 8] = v;
    }
    __syncthreads();
    const int c = t >> 2, g = t & 3;
    union {
      float f[4];
      float4 v;
    } fv[4];
    union {
      __bf16 b[16];
      uint4 u[2];
    } bv;
#pragma unroll
    for (int r = 0; r < 16; ++r) {
      const int pix = g * 16 + r;
      __bf16 b = Ll[pix * 64 + ((c >> 3) ^ (pix & 7)) * 8 + (c & 7)];
      bv.b[r] = b;
      fv[r >> 2].f[r & 3] = (float)b;
    }
    float* fd = xenc + ((size_t)n * 512 + c0 + c) * 1024 + p0 + g * 16;
#pragma unroll
    for (int r = 0; r < 4; ++r) *(float4*)(fd + r * 4) = fv[r].v;
    __bf16* bd = xeb + ((size_t)n * 512 + c0 + c) * 1024 + p0 + g * 16;
    *(uint4*)bd = bv.u[0];
    *(uint4*)(bd + 8) = bv.u[1];
  }
}

// ---------------- VLAD aggregation: bf16 MFMA GEMM (4-deep pipeline) -------
__global__ __launch_bounds__(256) void vlad_gemm(
    const __bf16* __restrict__ saPb, const __bf16* __restrict__ xeb,
    float* __restrict__ vpart) {
  __shared__ __align__(16) __bf16 Al[4][64 * 32];
  __shared__ __align__(16) __bf16 Bl[4][128 * 32];

  const int t = threadIdx.x;
  const int cT = blockIdx.x, n = blockIdx.y, ks = blockIdx.z;
  const int lane = t & 63, wid = t >> 6;
  const int l16 = lane & 15, q = lane >> 4;
  const int wrow = wid >> 1, wcol = wid & 1;

  const int ar = t >> 2, acp = t & 3;
  const __bf16* asrc = saPb + (size_t)n * 65536 + (size_t)ar * 1024 + ks * 256 +
                       (acp ^ ((ar >> 1) & 3)) * 8;
  const int br0 = t >> 2, bcp0 = t & 3;
  const int br1 = (t + 256) >> 2, bcp1 = t & 3;
  const __bf16* bsrc0 = xeb + (size_t)n * 524288 +
                        (size_t)(cT * 128 + br0) * 1024 + ks * 256 +
                        (bcp0 ^ ((br0 >> 1) & 3)) * 8;
  const __bf16* bsrc1 = xeb + (size_t)n * 524288 +
                        (size_t)(cT * 128 + br1) * 1024 + ks * 256 +
                        (bcp1 ^ ((br1 >> 1) & 3)) * 8;

  const int ldsb = wid * 512;
  const int sw = (q ^ ((l16 >> 1) & 3)) * 8;

  f32x4 acc[2][4];
#pragma unroll
  for (int i = 0; i < 2; ++i)
#pragma unroll
    for (int j = 0; j < 4; ++j) acc[i][j] = (f32x4){0.f, 0.f, 0.f, 0.f};

  // prologue: issue tiles 0..2 (3 loads each)
#pragma unroll
  for (int p = 0; p < 3; ++p) {
    GLDS16(asrc + p * 32, (__bf16*)Al[p] + ldsb);
    GLDS16(bsrc0 + p * 32, (__bf16*)Bl[p] + ldsb);
    GLDS16(bsrc1 + p * 32, (__bf16*)Bl[p] + 2048 + ldsb);
  }
  asm volatile("s_waitcnt vmcnt(6)" ::: "memory");  // tile0 done; 1,2 fly
  __builtin_amdgcn_s_barrier();

#pragma unroll 1
  for (int kc = 0; kc < 8; ++kc) {
    const __bf16* Ab = Al[kc & 3];
    const __bf16* Bb = Bl[kc & 3];
    // A: register reads
    bf16x8 af[2], bf[4];
#pragma unroll
    for (int i = 0; i < 2; ++i)
      af[i] = *(const bf16x8*)&Ab[(wrow * 32 + i * 16 + l16) * 32 + sw];
#pragma unroll
    for (int i = 0; i < 4; ++i)
      bf[i] = *(const bf16x8*)&Bb[(wcol * 64 + i * 16 + l16) * 32 + sw];
    // B: reads landed before buffer reuse
    asm volatile("s_waitcnt lgkmcnt(0)" ::: "memory");
    __builtin_amdgcn_sched_barrier(0);
    __builtin_amdgcn_s_barrier();
    // C: issue tile kc+3
    if (kc + 3 < 8) {
      GLDS16(asrc + (kc + 3) * 32, (__bf16*)Al[(kc + 3) & 3] + ldsb);
      GLDS16(bsrc0 + (kc + 3) * 32, (__bf16*)Bl[(kc + 3) & 3] + ldsb);
      GLDS16(bsrc1 + (kc + 3) * 32, (__bf16*)Bl[(kc + 3) & 3] + 2048 + ldsb);
    }
    // D: MFMA
#pragma unroll
    for (int mt = 0; mt < 2; ++mt)
#pragma unroll
      for (int nt = 0; nt < 4; ++nt)
        acc[mt][nt] = __builtin_amdgcn_mfma_f32_16x16x32_bf16(
            af[mt], bf[nt], acc[mt][nt], 0, 0, 0);
    // E/F: counted wait — tile kc+1 ready; kc+2, kc+3 stay in flight
    if (kc < 5)
      asm volatile("s_waitcnt vmcnt(6)" ::: "memory");
    else
      asm volatile("s_waitcnt vmcnt(0)" ::: "memory");
    __builtin_amdgcn_s_barrier();
  }

  float* vp = vpart + (size_t)(ks * 16 + n) * 32768;
#pragma unroll
  for (int mt = 0; mt < 2; ++mt) {
    const int krow = wrow * 32 + mt * 16 + q * 4;
#pragma unroll
    for (int nt = 0; nt < 4; ++nt) {
      const int ccol = cT * 128 + wcol * 64 + nt * 16 + l16;
#pragma unroll
      for (int r = 0; r < 4; ++r)
        vp[(size_t)(krow + r) * 512 + ccol] = acc[mt][nt][r];
    }
  }
}

// ---------------- intra-norm (sums 4 K-split partials) ---------------------
__global__ __launch_bounds__(64) void intra_norm(float* __restrict__ vraw,
                                                 const float* __restrict__ vpart,
                                                 const float* __restrict__ S,
                                                 const float* __restrict__ cent,
                                                 float* __restrict__ gss) {
  const int b = blockIdx.x;  // n*64 + k
  const int n = b >> 6, k = b & 63;
  const int lane = threadIdx.x;
  const float s = S[b];
  float v[8];
  float ss = 0.f;
#pragma unroll
  for (int j = 0; j < 8; ++j) {
    const int c = lane * 8 + j;
    const size_t off = (size_t)b * 512 + c;
    float val = vpart[off] + vpart[524288 + off] + vpart[2 * 524288 + off] +
                vpart[3 * 524288 + off] - s * cent[k * 512 + c];
    v[j] = val;
    ss += val * val;
  }
#pragma unroll
  for (int off = 1; off < 64; off <<= 1) ss += __shfl_xor(ss, off);
  const float rn = 1.0f / fmaxf(sqrtf(ss), 1e-12f);
#pragma unroll
  for (int j = 0; j < 8; ++j) vraw[(size_t)b * 512 + lane * 8 + j] = v[j] * rn;
  if (lane == 0) atomicAdd(&gss[n], ss * rn * rn);
}

__global__ __launch_bounds__(256) void finalize(const float* __restrict__ vraw,
                                                const float* __restrict__ gss,
                                                float* __restrict__ out) {
  const int base = blockIdx.x * 1024 + threadIdx.x;
#pragma unroll
  for (int j = 0; j < 4; ++j) {
    const int id = base + j * 256;
    const int n = id >> 15;
    out[id] = vraw[id] * (1.0f / fmaxf(sqrtf(gss[n]), 1e-12f));
  }
}

// ---------------- fused prep: zero_border + misc + xform + wt_prep ---------
// grid layout: [0,1056) zero-border, [1056,1191) misc, [1191,1703) xform,
// [1703,2727) wt_prep. All independent writes; fusing overlaps them across
// CUs and drops 3 launch gaps.
__global__ __launch_bounds__(256) void prep_all(
    const float* __restrict__ x, const float* __restrict__ w1,
    const float* __restrict__ w2, const float* __restrict__ g,
    const float* __restrict__ b, const float* __restrict__ m,
    const float* __restrict__ v, const float* __restrict__ wA,
    __bf16* __restrict__ xpad, __bf16* __restrict__ hpad,
    __bf16* __restrict__ wt1, __bf16* __restrict__ wt2,
    float* __restrict__ scale, float* __restrict__ shift,
    __bf16* __restrict__ watb, float* __restrict__ Sz) {
  __shared__ float Lw[4608];
  const int bx = blockIdx.x;
  const int t = threadIdx.x;

  if (bx < 1056) {
    // ---- zero the 132-pixel pad ring of xpad/hpad ----
    const int which = bx >= 528;
    const int id = (which ? bx - 528 : bx) * 256 + t;  // 0..135167
    const int n = id / 8448;
    const int rem = id - n * 8448;
    const int pb = rem >> 6;  // 0..131 border pixel
    const int c8 = rem & 63;
    int h, w;
    if (pb < 34) {
      h = 0;
      w = pb;
    } else if (pb < 68) {
      h = 33;
      w = pb - 34;
    } else {
      const int r2 = pb - 68;
      h = 1 + (r2 >> 1);
      w = (r2 & 1) * 33;
    }
    __bf16* base = which ? hpad : xpad;
    *(uint4*)(base + ((size_t)n * 1156 + h * 34 + w) * 512 + c8 * 8) =
        (uint4){0u, 0u, 0u, 0u};
  } else if (bx < 1191) {
    // ---- misc: BN fold, watb swizzle, S zero ----
    const int i = (bx - 1056) * 256 + t;
    if (i < 512) {
      float sc = g[i] / sqrtf(v[i] + 1e-5f);
      scale[i] = sc;
      shift[i] = b[i] - m[i] * sc;
    } else if (i < 512 + 32768) {
      const int id = i - 512;
      const int k = id >> 9, j = id & 511;
      const int kt = j >> 5, cpos = (j >> 3) & 3, e = j & 7;
      const int c = kt * 32 + (cpos ^ ((k >> 1) & 3)) * 8 + e;
      watb[(size_t)k * 512 + j] = (__bf16)wA[(size_t)k * 512 + c];
    } else if (i < 512 + 32768 + 1040) {
      Sz[i - (512 + 32768)] = 0.f;
    }
  } else if (bx < 1703) {
    // ---- xform: x (fp32 NCHW) -> xpad (bf16 NHWC padded) ----
    const int bb = bx - 1191;
    const int n = bb >> 5, h = bb & 31;
    const int w = t & 31, cg = t >> 5;
    const float* src = x + ((size_t)n * 512 + cg * 64) * 1024 + h * 32 + w;
    __bf16* dst =
        xpad + ((size_t)n * 1156 + (h + 1) * 34 + (w + 1)) * 512 + cg * 64;
    float fv[64];
#pragma unroll
    for (int j = 0; j < 64; ++j) fv[j] = src[j * 1024];  // all loads in flight
#pragma unroll
    for (int jj = 0; jj < 8; ++jj) {
      union {
        __bf16 b8[8];
        uint4 u;
      } pk;
#pragma unroll
      for (int j = 0; j < 8; ++j) pk.b8[j] = (__bf16)fv[jj * 8 + j];
      *(uint4*)(dst + jj * 8) = pk.u;
    }
  } else {
    // ---- wt_prep: OIHW fp32 -> [o][kt*64 + p*8 + e] bf16, swizzle baked ---
    const int bb = bx - 1703;  // 0..1023
    const int o = bb & 511;
    const float* w = (bb >> 9) ? w2 : w1;
    __bf16* wt = (bb >> 9) ? wt2 : wt1;
#pragma unroll
    for (int i = 0; i < 18; ++i)
      Lw[t + 256 * i] = w[(size_t)o * 4608 + t + 256 * i];
    __syncthreads();
#pragma unroll
    for (int i = 0; i < 18; ++i) {
      const int idk = t + 256 * i;
      const int kt = idk >> 6;
      const int p = (idk >> 3) & 7, e = idk & 7;
      const int logical = p ^ (o & 7);
      const int k2 = kt * 64 + logical * 8 + e;
      const int tap = k2 >> 9, ci = k2 & 511;
      wt[(size_t)o * 4608 + idk] = (__bf16)Lw[ci * 9 + tap];
    }
  }
}

// ---------------------------------------------------------------------------
extern "C" void kernel_launch(void* const* d_in, const int* in_sizes, int n_in,
                              void* d_out, int out_size, void* d_ws,
                              size_t ws_size, hipStream_t stream) {
  const float* x = (const float*)d_in[0];
  const float* w1 = (const float*)d_in[1];
  const float* gam = (const float*)d_in[2];
  const float* bet = (const float*)d_in[3];
  const float* mean = (const float*)d_in[4];
  const float* var = (const float*)d_in[5];
  const float* w2 = (const float*)d_in[6];
  const float* wA = (const float*)d_in[7];
  const float* cent = (const float*)d_in[8];
  float* out = (float*)d_out;

  char* ws = (char*)d_ws;
  __bf16* Wt1 = (__bf16*)(ws + 0);          // 4,718,592 (dead after conv1)
  __bf16* Wt2 = (__bf16*)(ws + 4718592);    // 4,718,592 (dead after conv2)
  __bf16* xpad = (__bf16*)(ws + 9437184);   // 18,939,904 (dead after conv1)
  __bf16* xebT = (__bf16*)(ws + 9437184);   // alias: 16,777,216 (conv2 out)
  __bf16* saPb = (__bf16*)(ws + 26214400);  // 2,097,152
  __bf16* hpad = (__bf16*)(ws + 28377088);  // 18,939,904 (dead after conv2)
  __bf16* xeb = (__bf16*)(ws + 28377088);   // alias: 16,777,216 (expand out)
  float* vpart = (float*)(ws + 0);          // alias Wt1/2: 8,388,608
  float* vraw = (float*)(ws + 8388608);     // alias: 2,097,152
  float* scale = (float*)(ws + 47316992);   // 2048 B
  float* shift = (float*)(ws + 47319040);   // 2048 B
  __bf16* watb = (__bf16*)(ws + 47321088);  // 65,536 B
  float* S = (float*)(ws + 47386624);       // 4096 B
  float* gss = (float*)(ws + 47390720);     // 64 B

  float* xenc = out + 524288;  // output 1 (x_enc, fp32 NCHW)

  prep_all<<<2727, 256, 0, stream>>>(x, w1, w2, gam, bet, mean, var, wA, xpad,
                                     hpad, Wt1, Wt2, scale, shift, watb, S);

  conv_gemm<0><<<dim3(128, 4), 256, 0, stream>>>(xpad, Wt1, scale, shift, hpad);
  conv_gemm<1><<<dim3(128, 4), 256, 0, stream>>>(hpad, Wt2, nullptr, nullptr,
                                                 xebT);

  post_conv<<<2304, 256, 0, stream>>>(xebT, watb, saPb, S, xenc, xeb);
  vlad_gemm<<<dim3(4, 16, 4), 256, 0, stream>>>(saPb, xeb, vpart);
  intra_norm<<<1024, 64, 0, stream>>>(vraw, vpart, S, cent, gss);
  finalize<<<512, 256, 0, stream>>>(vraw, gss, out);
}

// Round 11
// 298.413 us; speedup vs baseline: 2.2215x; 1.0150x over previous
//
#include <hip/hip_runtime.h>
#include <math.h>

// ---------------------------------------------------------------------------
// NetVLAD on gfx950.  (round-7/10 structure — measured best 302.9 us.)
// conv1/conv2: implicit GEMM, v_mfma_f32_16x16x32_bf16, 128x128 tile, BK=64,
//   2 blocks/CU — FROZEN: W double-buffer, TWO barriers per step, counted
//   vmcnt(4), W(s+2) in flight across barriers, halo(cc+1) FIFO-first at
//   tap==8, T5 setprio.  (256x128 tile: -55%; W triple-buffer: -17%;
//   coop-fused tail: grid.sync ~100us/sync -> 415us tail. All reverted.)
// NEW this round: assign_softmax and vlad_gemm process TWO K-tiles per
//   iteration (4 LDS buffers already present; addressing unchanged) —
//   barriers 32->16 (assign) and 16->8 (vlad). These kernels run 1 block/CU
//   latency-bound with ~8-16KB DMA/iter: per-iteration barrier+waitcnt chain
//   dominates, so halving iterations at constant traffic is the lever.
// post_conv: fused assign_softmax (256 blocks, first) + expand_x (2048).
// prep_all: fused prep.
// Fragment layouts (HW-verified): A/B: idx=lane&15, k=(lane>>4)*8+j;
// C/D: col=lane&15 (B idx), row=(lane>>4)*4+reg (A idx).
// ---------------------------------------------------------------------------

typedef __bf16 bf16x8 __attribute__((ext_vector_type(8)));
typedef float f32x4 __attribute__((ext_vector_type(4)));

#define GLDS16(gp, lp)                                                  \
  __builtin_amdgcn_global_load_lds(                                     \
      (const __attribute__((address_space(1))) void*)(gp),              \
      (__attribute__((address_space(3))) void*)(lp), 16, 0, 0)

// ---------------- conv as implicit GEMM, halo-tiled, BK=64 -----------------
// grid (128 pixel-tiles, 4 o-tiles), block 256 = 4 waves (2x2)
// MODE 0: BN+ReLU -> padded NHWC bf16 (hpad).
// MODE 1: xebT bf16 [n][pix][512] (c-contiguous), no BN.
template <int MODE>
__global__ __launch_bounds__(256) void conv_gemm(
    const __bf16* __restrict__ in,  // padded NHWC bf16 [16][34][34][512]
    const __bf16* __restrict__ wt,  // prepacked+swizzled [512][72*64]
    const float* __restrict__ scale, const float* __restrict__ shift,
    __bf16* __restrict__ outp) {
  __shared__ __align__(16) __bf16 Hl[6 * 42 * 64];   // 16128 elem, 31.5 KB
  __shared__ __align__(16) __bf16 Wl[2 * 128 * 64];  // 32 KB (double-buffered)

  const int t = threadIdx.x;
  const int bx = blockIdx.x, oT = blockIdx.y;
  const int lane = t & 63, wid = t >> 6;
  const int l16 = lane & 15, q = lane >> 4;
  const int wrow = wid >> 1, wcol = wid & 1;

  const int n = bx >> 3;
  const int trow0 = (bx & 7) * 4;  // first pixel row of this 128-pixel tile

  // ---- W staging: 4 chunks/thread; Wl[buf][row][phys8] = row*64 + phys*8
  const int swr = t >> 3, sp = t & 7;
  const __bf16* wsrc[4];
#pragma unroll
  for (int i = 0; i < 4; ++i)
    wsrc[i] = wt + (size_t)(oT * 128 + 32 * i + swr) * 4608 + sp * 8;

  // ---- halo staging: 8 chunks/thread over 6 rows x 42 cols x 8 c8-chunks
  const __bf16* inb = in + (size_t)n * (1156 * 512);
  const __bf16* hsrc[8];
  bool hval[8];
#pragma unroll
  for (int i = 0; i < 8; ++i) {
    const int jj = t + 256 * i;
    hval[i] = jj < 2016;
    const int hr = jj / 336;
    const int hrem = jj - hr * 336;
    const int hw = hrem >> 3, hc8 = hrem & 7;
    hsrc[i] = inb + ((size_t)((trow0 + hr) * 34 + hw)) * 512 +
              (hc8 ^ (hw & 7)) * 8;
  }

  // ---- fragment read constants
  const int c0 = (q ^ (l16 & 7)) * 8;
  const int c1 = ((4 + q) ^ (l16 & 7)) * 8;
  int aoff[4], prow_[4], pcol_[4];
#pragma unroll
  for (int i = 0; i < 4; ++i) {
    aoff[i] = (wrow * 64 + i * 16 + l16) * 64;
    const int p = wcol * 64 + i * 16 + l16;
    prow_[i] = p >> 5;
    pcol_[i] = p & 31;
  }

  f32x4 acc[4][4];
#pragma unroll
  for (int i = 0; i < 4; ++i)
#pragma unroll
    for (int j = 0; j < 4; ++j) acc[i][j] = (f32x4){0.f, 0.f, 0.f, 0.f};

  // ---- prologue: halo(cc=0), W(step0)->Wl[0], W(step1)->Wl[1] ------------
  // step s has (cc,tap) = (s/9, s%9); woffs = (tap*8+cc)*64.
#pragma unroll
  for (int i = 0; i < 8; ++i)
    if (hval[i]) GLDS16(hsrc[i], Hl + (t + 256 * i) * 8);
#pragma unroll
  for (int i = 0; i < 4; ++i)
    GLDS16(wsrc[i], Wl + (t + 256 * i) * 8);  // step0: woffs=0
#pragma unroll
  for (int i = 0; i < 4; ++i)
    GLDS16(wsrc[i] + 512, Wl + 8192 + (t + 256 * i) * 8);  // step1: woffs=512
  // outstanding: halo(8) + W0(4) + W1(4). Wait halo+W0; keep W1 in flight.
  asm volatile("s_waitcnt vmcnt(4)" ::: "memory");
  __builtin_amdgcn_s_barrier();

  int tap = 0, dh = 0, dw = 0, cc = 0;  // step s
  int tap2 = 2, cc2 = 0;                // step s+2 (prefetch target)

#pragma unroll 1
  for (int s = 0; s < 72; ++s) {
    const int buf = (s & 1) << 13;  // 0 or 8192 elements
    const __bf16* Wb = Wl + buf;

    // A: fragment reads for step s
    bf16x8 aw[4][2], bp[4][2];
#pragma unroll
    for (int i = 0; i < 4; ++i) {
      aw[i][0] = *(const bf16x8*)&Wb[aoff[i] + c0];
      aw[i][1] = *(const bf16x8*)&Wb[aoff[i] + c1];
    }
#pragma unroll
    for (int i = 0; i < 4; ++i) {
      const int col = pcol_[i] + dw;
      const int rb = (prow_[i] + dh) * 2688 + col * 64;
      const int xr = col & 7;
      bp[i][0] = *(const bf16x8*)&Hl[rb + (q ^ xr) * 8];
      bp[i][1] = *(const bf16x8*)&Hl[rb + ((4 + q) ^ xr) * 8];
    }
    // B/C: reads landed in regs (cross-wave WAR vs incoming DMA), then sync.
    asm volatile("s_waitcnt lgkmcnt(0)" ::: "memory");
    __builtin_amdgcn_sched_barrier(0);
    __builtin_amdgcn_s_barrier();

    // D: issue next-halo FIRST (FIFO: so vmcnt(4) below covers it), then
    //    W(s+2) into the buffer step s just finished reading.
    if (tap == 8 && cc < 7) {
#pragma unroll
      for (int i = 0; i < 8; ++i)
        if (hval[i]) GLDS16(hsrc[i] + (cc + 1) * 64, Hl + (t + 256 * i) * 8);
    }
    if (s < 70) {
      const int woffs2 = (tap2 * 8 + cc2) * 64;
#pragma unroll
      for (int i = 0; i < 4; ++i)
        GLDS16(wsrc[i] + woffs2, Wl + buf + (t + 256 * i) * 8);
    }

    // E: MFMA cluster (T5)
    __builtin_amdgcn_s_setprio(1);
#pragma unroll
    for (int kh = 0; kh < 2; ++kh)
#pragma unroll
      for (int mt = 0; mt < 4; ++mt)
#pragma unroll
        for (int nt = 0; nt < 4; ++nt)
          acc[mt][nt] = __builtin_amdgcn_mfma_f32_16x16x32_bf16(
              aw[mt][kh], bp[nt][kh], acc[mt][nt], 0, 0, 0);
    __builtin_amdgcn_s_setprio(0);

    // F/G: counted wait — drain {W(s+1), halo-if-issued}; W(s+2) stays in
    // flight across the barrier. Tail drains fully.
    if (s < 70)
      asm volatile("s_waitcnt vmcnt(4)" ::: "memory");
    else
      asm volatile("s_waitcnt vmcnt(0)" ::: "memory");
    __builtin_amdgcn_s_barrier();

    // advance step / prefetch counters
    ++tap;
    ++dw;
    if (dw == 3) {
      dw = 0;
      ++dh;
    }
    if (tap == 9) {
      tap = 0;
      dh = 0;
      dw = 0;
      ++cc;
    }
    if (++tap2 == 9) {
      tap2 = 0;
      ++cc2;
    }
  }

  // ---- epilogue ----
#pragma unroll
  for (int nt = 0; nt < 4; ++nt) {
    const int m_l = wcol * 64 + nt * 16 + l16;
    const int mg2 = bx * 128 + m_l;
    const int n2 = mg2 >> 10, pix2 = mg2 & 1023;
#pragma unroll
    for (int mt = 0; mt < 4; ++mt) {
      const int ob = oT * 128 + wrow * 64 + mt * 16 + q * 4;
      f32x4 v = acc[mt][nt];
      union {
        __bf16 b[4];
        uint2 u;
      } pk;
      if (MODE == 0) {
        const f32x4 sc = *(const f32x4*)&scale[ob];
        const f32x4 sh = *(const f32x4*)&shift[ob];
#pragma unroll
        for (int r = 0; r < 4; ++r)
          pk.b[r] = (__bf16)fmaxf(v[r] * sc[r] + sh[r], 0.f);
        __bf16* dst = outp +
                      ((size_t)n2 * 1156 + ((pix2 >> 5) + 1) * 34 +
                       ((pix2 & 31) + 1)) * 512 + ob;
        *(uint2*)dst = pk.u;
      } else {
#pragma unroll
        for (int r = 0; r < 4; ++r) pk.b[r] = (__bf16)v[r];
        __bf16* dst = outp + ((size_t)n2 * 1024 + pix2) * 512 + ob;
        *(uint2*)dst = pk.u;
      }
    }
  }
}

// ---------------- fused post-conv2: assign_softmax + expand_x --------------
// bx < 256: assign_softmax (latency-bound long pole — dispatched first),
//   now 8 iterations x 2 K-tiles (was 16 x 1): barriers halved.
// bx >= 256: expand_x (BW-bound, fills remaining CUs).
__global__ __launch_bounds__(256) void post_conv(
    const __bf16* __restrict__ xebT, const __bf16* __restrict__ watb,
    __bf16* __restrict__ saPb, float* __restrict__ S,
    float* __restrict__ xenc, __bf16* __restrict__ xeb) {
  __shared__ __align__(16) __bf16 Al[4][64 * 32];
  __shared__ __align__(16) __bf16 Wlb[4][64 * 32];
  __shared__ float Sl[64];
  const int t = threadIdx.x;
  const int bx0 = blockIdx.x;

  if (bx0 < 256) {
    // ======== assign_softmax (4-buffer, 2 tiles/iter) ========
    const int pt = bx0 & 15, n = bx0 >> 4;
    const int lane = t & 63, wid = t >> 6;
    const int l16 = lane & 15, q = lane >> 4;
    if (t < 64) Sl[t] = 0.f;

    const int arow = t >> 2;  // pixel row 0..63
    const __bf16* asrc = xebT + ((size_t)n * 1024 + pt * 64 + arow) * 512 +
                         ((t & 3) ^ ((arow >> 1) & 3)) * 8;
    const __bf16* wsrc = watb + (size_t)(t >> 2) * 512 + (t & 3) * 8;
    const int ldsb = wid * 512;
    const int sw = (q ^ ((l16 >> 1) & 3)) * 8;
    const int pnoff = (t >> 2) * 32 + (t & 3) * 8;

    f32x4 acc[4];
#pragma unroll
    for (int i = 0; i < 4; ++i) acc[i] = (f32x4){0.f, 0.f, 0.f, 0.f};
    float pn = 0.f;

    // prologue: issue tiles 0..3 (2 loads each, 8 total)
#pragma unroll
    for (int p = 0; p < 4; ++p) {
      GLDS16(asrc + p * 32, (__bf16*)Al[p] + ldsb);
      GLDS16(wsrc + p * 32, (__bf16*)Wlb[p] + ldsb);
    }
    asm volatile("s_waitcnt vmcnt(4)" ::: "memory");  // tiles 0,1 done
    __builtin_amdgcn_s_barrier();

#pragma unroll 1
    for (int J = 0; J < 8; ++J) {
      const int ka0 = 2 * J, kb0 = 2 * J + 1;
      const __bf16* Ab0 = Al[ka0 & 3];
      const __bf16* Wb0 = Wlb[ka0 & 3];
      const __bf16* Ab1 = Al[kb0 & 3];
      const __bf16* Wb1 = Wlb[kb0 & 3];
      // A: register reads of BOTH tiles
      bf16x8 pv0 = *(const bf16x8*)&Ab0[pnoff];
      bf16x8 pv1 = *(const bf16x8*)&Ab1[pnoff];
      bf16x8 pf0 = *(const bf16x8*)&Ab0[(wid * 16 + l16) * 32 + sw];
      bf16x8 pf1 = *(const bf16x8*)&Ab1[(wid * 16 + l16) * 32 + sw];
      bf16x8 wf0[4], wf1[4];
#pragma unroll
      for (int ka = 0; ka < 4; ++ka) {
        wf0[ka] = *(const bf16x8*)&Wb0[(ka * 16 + l16) * 32 + sw];
        wf1[ka] = *(const bf16x8*)&Wb1[(ka * 16 + l16) * 32 + sw];
      }
      // B: all waves' reads landed before buffer reuse
      asm volatile("s_waitcnt lgkmcnt(0)" ::: "memory");
      __builtin_amdgcn_sched_barrier(0);
      __builtin_amdgcn_s_barrier();
      // C: issue tiles 2J+4, 2J+5 into the two buffers just freed
      if (J < 6) {
        GLDS16(asrc + (2 * J + 4) * 32, (__bf16*)Al[ka0 & 3] + ldsb);
        GLDS16(wsrc + (2 * J + 4) * 32, (__bf16*)Wlb[ka0 & 3] + ldsb);
        GLDS16(asrc + (2 * J + 5) * 32, (__bf16*)Al[kb0 & 3] + ldsb);
        GLDS16(wsrc + (2 * J + 5) * 32, (__bf16*)Wlb[kb0 & 3] + ldsb);
      }
      // D: compute both tiles
#pragma unroll
      for (int j = 0; j < 8; ++j) {
        float f0 = (float)pv0[j];
        pn = fmaf(f0, f0, pn);
        float f1 = (float)pv1[j];
        pn = fmaf(f1, f1, pn);
      }
#pragma unroll
      for (int ka = 0; ka < 4; ++ka) {
        acc[ka] = __builtin_amdgcn_mfma_f32_16x16x32_bf16(wf0[ka], pf0,
                                                          acc[ka], 0, 0, 0);
        acc[ka] = __builtin_amdgcn_mfma_f32_16x16x32_bf16(wf1[ka], pf1,
                                                          acc[ka], 0, 0, 0);
      }
      // E/F: counted wait — tiles 2J+2,2J+3 ready; 2J+4,2J+5 stay in flight
      if (J < 6)
        asm volatile("s_waitcnt vmcnt(4)" ::: "memory");
      else
        asm volatile("s_waitcnt vmcnt(0)" ::: "memory");
      __builtin_amdgcn_s_barrier();
    }
    pn += __shfl_xor(pn, 1);
    pn += __shfl_xor(pn, 2);
    const float rn = 1.0f / fmaxf(sqrtf(__shfl(pn, l16 * 4)), 1e-12f);

    float sc[16];
    float m = -3.4e38f;
#pragma unroll
    for (int ka = 0; ka < 4; ++ka)
#pragma unroll
      for (int r = 0; r < 4; ++r) {
        float v = acc[ka][r] * rn;
        sc[ka * 4 + r] = v;
        m = fmaxf(m, v);
      }
    m = fmaxf(m, __shfl_xor(m, 16));
    m = fmaxf(m, __shfl_xor(m, 32));
    float s = 0.f;
#pragma unroll
    for (int j = 0; j < 16; ++j) {
      sc[j] = __expf(sc[j] - m);
      s += sc[j];
    }
    s += __shfl_xor(s, 16);
    s += __shfl_xor(s, 32);
    const float inv = 1.0f / s;
    const int pixg = pt * 64 + wid * 16 + l16;
#pragma unroll
    for (int j = 0; j < 16; ++j) {
      const int k = (j >> 2) * 16 + q * 4 + (j & 3);
      float sa = sc[j] * inv;
      sc[j] = sa;
      saPb[((size_t)n * 64 + k) * 1024 + pixg] = (__bf16)(sa * rn);
    }
#pragma unroll
    for (int j = 0; j < 16; ++j) {
      float v = sc[j];
      v += __shfl_xor(v, 1);
      v += __shfl_xor(v, 2);
      v += __shfl_xor(v, 4);
      v += __shfl_xor(v, 8);
      sc[j] = v;
    }
    if (l16 == 0) {
#pragma unroll
      for (int j = 0; j < 16; ++j)
        atomicAdd(&Sl[(j >> 2) * 16 + q * 4 + (j & 3)], sc[j]);
    }
    __syncthreads();
    if (t < 64) atomicAdd(&S[n * 64 + t], Sl[t]);
  } else {
    // ======== expand_x: xebT [pix][c] -> xenc fp32 [c][pix] + xeb bf16 ====
    const int e = bx0 - 256;
    const int cc = e & 7, ptile = (e >> 3) & 15, n = e >> 7;
    __bf16* Ll = (__bf16*)Al;  // 8 KB carve
    const int p0 = ptile * 64, c0 = cc * 64;
#pragma unroll
    for (int i = 0; i < 2; ++i) {
      const int u = t * 2 + i;
      const int pix = u >> 3, c8 = u & 7;
      uint4 v = *(const uint4*)&xebT[((size_t)n * 1024 + p0 + pix) * 512 + c0 +
                                     c8 * 8];
      *(uint4*)&Ll[pix * 64 + (c8 ^ (pix & 7)) * 8] = v;
    }
    __syncthreads();
    const int c = t >> 2, g = t & 3;
    union {
      float f[4];
      float4 v;
    } fv[4];
    union {
      __bf16 b[16];
      uint4 u[2];
    } bv;
#pragma unroll
    for (int r = 0; r < 16; ++r) {
      const int pix = g * 16 + r;
      __bf16 b = Ll[pix * 64 + ((c >> 3) ^ (pix & 7)) * 8 + (c & 7)];
      bv.b[r] = b;
      fv[r >> 2].f[r & 3] = (float)b;
    }
    float* fd = xenc + ((size_t)n * 512 + c0 + c) * 1024 + p0 + g * 16;
#pragma unroll
    for (int r = 0; r < 4; ++r) *(float4*)(fd + r * 4) = fv[r].v;
    __bf16* bd = xeb + ((size_t)n * 512 + c0 + c) * 1024 + p0 + g * 16;
    *(uint4*)bd = bv.u[0];
    *(uint4*)(bd + 8) = bv.u[1];
  }
}

// ---------------- VLAD aggregation: bf16 MFMA GEMM (2 tiles/iter) ----------
__global__ __launch_bounds__(256) void vlad_gemm(
    const __bf16* __restrict__ saPb, const __bf16* __restrict__ xeb,
    float* __restrict__ vpart) {
  __shared__ __align__(16) __bf16 Al[4][64 * 32];
  __shared__ __align__(16) __bf16 Bl[4][128 * 32];

  const int t = threadIdx.x;
  const int cT = blockIdx.x, n = blockIdx.y, ks = blockIdx.z;
  const int lane = t & 63, wid = t >> 6;
  const int l16 = lane & 15, q = lane >> 4;
  const int wrow = wid >> 1, wcol = wid & 1;

  const int ar = t >> 2, acp = t & 3;
  const __bf16* asrc = saPb + (size_t)n * 65536 + (size_t)ar * 1024 + ks * 256 +
                       (acp ^ ((ar >> 1) & 3)) * 8;
  const int br0 = t >> 2, bcp0 = t & 3;
  const int br1 = (t + 256) >> 2, bcp1 = t & 3;
  const __bf16* bsrc0 = xeb + (size_t)n * 524288 +
                        (size_t)(cT * 128 + br0) * 1024 + ks * 256 +
                        (bcp0 ^ ((br0 >> 1) & 3)) * 8;
  const __bf16* bsrc1 = xeb + (size_t)n * 524288 +
                        (size_t)(cT * 128 + br1) * 1024 + ks * 256 +
                        (bcp1 ^ ((br1 >> 1) & 3)) * 8;

  const int ldsb = wid * 512;
  const int sw = (q ^ ((l16 >> 1) & 3)) * 8;

  f32x4 acc[2][4];
#pragma unroll
  for (int i = 0; i < 2; ++i)
#pragma unroll
    for (int j = 0; j < 4; ++j) acc[i][j] = (f32x4){0.f, 0.f, 0.f, 0.f};

  // prologue: issue tiles 0..3 (3 loads each, 12 total)
#pragma unroll
  for (int p = 0; p < 4; ++p) {
    GLDS16(asrc + p * 32, (__bf16*)Al[p] + ldsb);
    GLDS16(bsrc0 + p * 32, (__bf16*)Bl[p] + ldsb);
    GLDS16(bsrc1 + p * 32, (__bf16*)Bl[p] + 2048 + ldsb);
  }
  asm volatile("s_waitcnt vmcnt(6)" ::: "memory");  // tiles 0,1 done
  __builtin_amdgcn_s_barrier();

#pragma unroll 1
  for (int J = 0; J < 4; ++J) {
    const int ka0 = 2 * J, kb0 = 2 * J + 1;
    const __bf16* Ab0 = Al[ka0 & 3];
    const __bf16* Bb0 = Bl[ka0 & 3];
    const __bf16* Ab1 = Al[kb0 & 3];
    const __bf16* Bb1 = Bl[kb0 & 3];
    // A: register reads of BOTH tiles
    bf16x8 af0[2], bf0[4], af1[2], bf1[4];
#pragma unroll
    for (int i = 0; i < 2; ++i) {
      af0[i] = *(const bf16x8*)&Ab0[(wrow * 32 + i * 16 + l16) * 32 + sw];
      af1[i] = *(const bf16x8*)&Ab1[(wrow * 32 + i * 16 + l16) * 32 + sw];
    }
#pragma unroll
    for (int i = 0; i < 4; ++i) {
      bf0[i] = *(const bf16x8*)&Bb0[(wcol * 64 + i * 16 + l16) * 32 + sw];
      bf1[i] = *(const bf16x8*)&Bb1[(wcol * 64 + i * 16 + l16) * 32 + sw];
    }
    // B: reads landed before buffer reuse
    asm volatile("s_waitcnt lgkmcnt(0)" ::: "memory");
    __builtin_amdgcn_sched_barrier(0);
    __builtin_amdgcn_s_barrier();
    // C: issue tiles 2J+4, 2J+5
    if (J < 2) {
      GLDS16(asrc + (2 * J + 4) * 32, (__bf16*)Al[ka0 & 3] + ldsb);
      GLDS16(bsrc0 + (2 * J + 4) * 32, (__bf16*)Bl[ka0 & 3] + ldsb);
      GLDS16(bsrc1 + (2 * J + 4) * 32, (__bf16*)Bl[ka0 & 3] + 2048 + ldsb);
      GLDS16(asrc + (2 * J + 5) * 32, (__bf16*)Al[kb0 & 3] + ldsb);
      GLDS16(bsrc0 + (2 * J + 5) * 32, (__bf16*)Bl[kb0 & 3] + ldsb);
      GLDS16(bsrc1 + (2 * J + 5) * 32, (__bf16*)Bl[kb0 & 3] + 2048 + ldsb);
    }
    // D: MFMA both tiles
#pragma unroll
    for (int mt = 0; mt < 2; ++mt)
#pragma unroll
      for (int nt = 0; nt < 4; ++nt) {
        acc[mt][nt] = __builtin_amdgcn_mfma_f32_16x16x32_bf16(
            af0[mt], bf0[nt], acc[mt][nt], 0, 0, 0);
        acc[mt][nt] = __builtin_amdgcn_mfma_f32_16x16x32_bf16(
            af1[mt], bf1[nt], acc[mt][nt], 0, 0, 0);
      }
    // E/F: counted wait — tiles 2J+2,2J+3 ready; 2J+4,2J+5 stay in flight
    if (J < 2)
      asm volatile("s_waitcnt vmcnt(6)" ::: "memory");
    else
      asm volatile("s_waitcnt vmcnt(0)" ::: "memory");
    __builtin_amdgcn_s_barrier();
  }

  float* vp = vpart + (size_t)(ks * 16 + n) * 32768;
#pragma unroll
  for (int mt = 0; mt < 2; ++mt) {
    const int krow = wrow * 32 + mt * 16 + q * 4;
#pragma unroll
    for (int nt = 0; nt < 4; ++nt) {
      const int ccol = cT * 128 + wcol * 64 + nt * 16 + l16;
#pragma unroll
      for (int r = 0; r < 4; ++r)
        vp[(size_t)(krow + r) * 512 + ccol] = acc[mt][nt][r];
    }
  }
}

// ---------------- intra-norm (sums 4 K-split partials) ---------------------
__global__ __launch_bounds__(64) void intra_norm(float* __restrict__ vraw,
                                                 const float* __restrict__ vpart,
                                                 const float* __restrict__ S,
                                                 const float* __restrict__ cent,
                                                 float* __restrict__ gss) {
  const int b = blockIdx.x;  // n*64 + k
  const int n = b >> 6, k = b & 63;
  const int lane = threadIdx.x;
  const float s = S[b];
  float v[8];
  float ss = 0.f;
#pragma unroll
  for (int j = 0; j < 8; ++j) {
    const int c = lane * 8 + j;
    const size_t off = (size_t)b * 512 + c;
    float val = vpart[off] + vpart[524288 + off] + vpart[2 * 524288 + off] +
                vpart[3 * 524288 + off] - s * cent[k * 512 + c];
    v[j] = val;
    ss += val * val;
  }
#pragma unroll
  for (int off = 1; off < 64; off <<= 1) ss += __shfl_xor(ss, off);
  const float rn = 1.0f / fmaxf(sqrtf(ss), 1e-12f);
#pragma unroll
  for (int j = 0; j < 8; ++j) vraw[(size_t)b * 512 + lane * 8 + j] = v[j] * rn;
  if (lane == 0) atomicAdd(&gss[n], ss * rn * rn);
}

__global__ __launch_bounds__(256) void finalize(const float* __restrict__ vraw,
                                                const float* __restrict__ gss,
                                                float* __restrict__ out) {
  const int base = blockIdx.x * 1024 + threadIdx.x;
#pragma unroll
  for (int j = 0; j < 4; ++j) {
    const int id = base + j * 256;
    const int n = id >> 15;
    out[id] = vraw[id] * (1.0f / fmaxf(sqrtf(gss[n]), 1e-12f));
  }
}

// ---------------- fused prep: zero_border + misc + xform + wt_prep ---------
// grid layout: [0,1056) zero-border, [1056,1191) misc, [1191,1703) xform,
// [1703,2727) wt_prep. All independent writes; fusing overlaps them across
// CUs and drops 3 launch gaps.
__global__ __launch_bounds__(256) void prep_all(
    const float* __restrict__ x, const float* __restrict__ w1,
    const float* __restrict__ w2, const float* __restrict__ g,
    const float* __restrict__ b, const float* __restrict__ m,
    const float* __restrict__ v, const float* __restrict__ wA,
    __bf16* __restrict__ xpad, __bf16* __restrict__ hpad,
    __bf16* __restrict__ wt1, __bf16* __restrict__ wt2,
    float* __restrict__ scale, float* __restrict__ shift,
    __bf16* __restrict__ watb, float* __restrict__ Sz) {
  __shared__ float Lw[4608];
  const int bx = blockIdx.x;
  const int t = threadIdx.x;

  if (bx < 1056) {
    // ---- zero the 132-pixel pad ring of xpad/hpad ----
    const int which = bx >= 528;
    const int id = (which ? bx - 528 : bx) * 256 + t;  // 0..135167
    const int n = id / 8448;
    const int rem = id - n * 8448;
    const int pb = rem >> 6;  // 0..131 border pixel
    const int c8 = rem & 63;
    int h, w;
    if (pb < 34) {
      h = 0;
      w = pb;
    } else if (pb < 68) {
      h = 33;
      w = pb - 34;
    } else {
      const int r2 = pb - 68;
      h = 1 + (r2 >> 1);
      w = (r2 & 1) * 33;
    }
    __bf16* base = which ? hpad : xpad;
    *(uint4*)(base + ((size_t)n * 1156 + h * 34 + w) * 512 + c8 * 8) =
        (uint4){0u, 0u, 0u, 0u};
  } else if (bx < 1191) {
    // ---- misc: BN fold, watb swizzle, S zero ----
    const int i = (bx - 1056) * 256 + t;
    if (i < 512) {
      float sc = g[i] / sqrtf(v[i] + 1e-5f);
      scale[i] = sc;
      shift[i] = b[i] - m[i] * sc;
    } else if (i < 512 + 32768) {
      const int id = i - 512;
      const int k = id >> 9, j = id & 511;
      const int kt = j >> 5, cpos = (j >> 3) & 3, e = j & 7;
      const int c = kt * 32 + (cpos ^ ((k >> 1) & 3)) * 8 + e;
      watb[(size_t)k * 512 + j] = (__bf16)wA[(size_t)k * 512 + c];
    } else if (i < 512 + 32768 + 1040) {
      Sz[i - (512 + 32768)] = 0.f;
    }
  } else if (bx < 1703) {
    // ---- xform: x (fp32 NCHW) -> xpad (bf16 NHWC padded) ----
    const int bb = bx - 1191;
    const int n = bb >> 5, h = bb & 31;
    const int w = t & 31, cg = t >> 5;
    const float* src = x + ((size_t)n * 512 + cg * 64) * 1024 + h * 32 + w;
    __bf16* dst =
        xpad + ((size_t)n * 1156 + (h + 1) * 34 + (w + 1)) * 512 + cg * 64;
    float fv[64];
#pragma unroll
    for (int j = 0; j < 64; ++j) fv[j] = src[j * 1024];  // all loads in flight
#pragma unroll
    for (int jj = 0; jj < 8; ++jj) {
      union {
        __bf16 b8[8];
        uint4 u;
      } pk;
#pragma unroll
      for (int j = 0; j < 8; ++j) pk.b8[j] = (__bf16)fv[jj * 8 + j];
      *(uint4*)(dst + jj * 8) = pk.u;
    }
  } else {
    // ---- wt_prep: OIHW fp32 -> [o][kt*64 + p*8 + e] bf16, swizzle baked ---
    const int bb = bx - 1703;  // 0..1023
    const int o = bb & 511;
    const float* w = (bb >> 9) ? w2 : w1;
    __bf16* wt = (bb >> 9) ? wt2 : wt1;
#pragma unroll
    for (int i = 0; i < 18; ++i)
      Lw[t + 256 * i] = w[(size_t)o * 4608 + t + 256 * i];
    __syncthreads();
#pragma unroll
    for (int i = 0; i < 18; ++i) {
      const int idk = t + 256 * i;
      const int kt = idk >> 6;
      const int p = (idk >> 3) & 7, e = idk & 7;
      const int logical = p ^ (o & 7);
      const int k2 = kt * 64 + logical * 8 + e;
      const int tap = k2 >> 9, ci = k2 & 511;
      wt[(size_t)o * 4608 + idk] = (__bf16)Lw[ci * 9 + tap];
    }
  }
}

// ---------------------------------------------------------------------------
extern "C" void kernel_launch(void* const* d_in, const int* in_sizes, int n_in,
                              void* d_out, int out_size, void* d_ws,
                              size_t ws_size, hipStream_t stream) {
  const float* x = (const float*)d_in[0];
  const float* w1 = (const float*)d_in[1];
  const float* gam = (const float*)d_in[2];
  const float* bet = (const float*)d_in[3];
  const float* mean = (const float*)d_in[4];
  const float* var = (const float*)d_in[5];
  const float* w2 = (const float*)d_in[6];
  const float* wA = (const float*)d_in[7];
  const float* cent = (const float*)d_in[8];
  float* out = (float*)d_out;

  char* ws = (char*)d_ws;
  __bf16* Wt1 = (__bf16*)(ws + 0);          // 4,718,592 (dead after conv1)
  __bf16* Wt2 = (__bf16*)(ws + 4718592);    // 4,718,592 (dead after conv2)
  __bf16* xpad = (__bf16*)(ws + 9437184);   // 18,939,904 (dead after conv1)
  __bf16* xebT = (__bf16*)(ws + 9437184);   // alias: 16,777,216 (conv2 out)
  __bf16* saPb = (__bf16*)(ws + 26214400);  // 2,097,152
  __bf16* hpad = (__bf16*)(ws + 28377088);  // 18,939,904 (dead after conv2)
  __bf16* xeb = (__bf16*)(ws + 28377088);   // alias: 16,777,216 (expand out)
  float* vpart = (float*)(ws + 0);          // alias Wt1/2: 8,388,608
  float* vraw = (float*)(ws + 8388608);     // alias: 2,097,152
  float* scale = (float*)(ws + 47316992);   // 2048 B
  float* shift = (float*)(ws + 47319040);   // 2048 B
  __bf16* watb = (__bf16*)(ws + 47321088);  // 65,536 B
  float* S = (float*)(ws + 47386624);       // 4096 B
  float* gss = (float*)(ws + 47390720);     // 64 B

  float* xenc = out + 524288;  // output 1 (x_enc, fp32 NCHW)

  prep_all<<<2727, 256, 0, stream>>>(x, w1, w2, gam, bet, mean, var, wA, xpad,
                                     hpad, Wt1, Wt2, scale, shift, watb, S);

  conv_gemm<0><<<dim3(128, 4), 256, 0, stream>>>(xpad, Wt1, scale, shift, hpad);
  conv_gemm<1><<<dim3(128, 4), 256, 0, stream>>>(hpad, Wt2, nullptr, nullptr,
                                                 xebT);

  post_conv<<<2304, 256, 0, stream>>>(xebT, watb, saPb, S, xenc, xeb);
  vlad_gemm<<<dim3(4, 16, 4), 256, 0, stream>>>(saPb, xeb, vpart);
  intra_norm<<<1024, 64, 0, stream>>>(vraw, vpart, S, cent, gss);
  finalize<<<512, 256, 0, stream>>>(vraw, gss, out);
}

// Round 13
// 297.446 us; speedup vs baseline: 2.2287x; 1.0033x over previous
//
#include <hip/hip_runtime.h>
#include <math.h>

// ---------------------------------------------------------------------------
// NetVLAD on gfx950.  (round-11 structure + norm_out fusion; resubmitted
// verbatim after round-12 infra failure — kernel was never executed.)
// conv1/conv2: implicit GEMM, v_mfma_f32_16x16x32_bf16, 128x128 tile, BK=64,
//   2 blocks/CU — FROZEN: W double-buffer, TWO barriers per step, counted
//   vmcnt(4), W(s+2) in flight across barriers, halo(cc+1) FIFO-first at
//   tap==8, T5 setprio.  (256x128 tile: -55%; W triple-buffer: -17%;
//   coop-fused tail: grid.sync ~100us/sync -> 415us tail. All reverted.)
// assign_softmax / vlad_gemm: 4 LDS buffers, TWO K-tiles per iteration
//   (barriers halved; measured -4.5us in round 11).
// norm_out fuses intra_norm + finalize — one block per image (16 blocks x
//   1024 thr, wave per (n,k)-row x4), values held in registers, gss reduced
//   in LDS, out written directly. Eliminates the vraw 2MB write + 2MB
//   re-read, the gss global atomics, and one launch+drain.
// post_conv: fused assign_softmax (256 blocks, first) + expand_x (2048).
// prep_all: fused prep.
// Fragment layouts (HW-verified): A/B: idx=lane&15, k=(lane>>4)*8+j;
// C/D: col=lane&15 (B idx), row=(lane>>4)*4+reg (A idx).
// ---------------------------------------------------------------------------

typedef __bf16 bf16x8 __attribute__((ext_vector_type(8)));
typedef float f32x4 __attribute__((ext_vector_type(4)));

#define GLDS16(gp, lp)                                                  \
  __builtin_amdgcn_global_load_lds(                                     \
      (const __attribute__((address_space(1))) void*)(gp),              \
      (__attribute__((address_space(3))) void*)(lp), 16, 0, 0)

// ---------------- conv as implicit GEMM, halo-tiled, BK=64 -----------------
// grid (128 pixel-tiles, 4 o-tiles), block 256 = 4 waves (2x2)
// MODE 0: BN+ReLU -> padded NHWC bf16 (hpad).
// MODE 1: xebT bf16 [n][pix][512] (c-contiguous), no BN.
template <int MODE>
__global__ __launch_bounds__(256) void conv_gemm(
    const __bf16* __restrict__ in,  // padded NHWC bf16 [16][34][34][512]
    const __bf16* __restrict__ wt,  // prepacked+swizzled [512][72*64]
    const float* __restrict__ scale, const float* __restrict__ shift,
    __bf16* __restrict__ outp) {
  __shared__ __align__(16) __bf16 Hl[6 * 42 * 64];   // 16128 elem, 31.5 KB
  __shared__ __align__(16) __bf16 Wl[2 * 128 * 64];  // 32 KB (double-buffered)

  const int t = threadIdx.x;
  const int bx = blockIdx.x, oT = blockIdx.y;
  const int lane = t & 63, wid = t >> 6;
  const int l16 = lane & 15, q = lane >> 4;
  const int wrow = wid >> 1, wcol = wid & 1;

  const int n = bx >> 3;
  const int trow0 = (bx & 7) * 4;  // first pixel row of this 128-pixel tile

  // ---- W staging: 4 chunks/thread; Wl[buf][row][phys8] = row*64 + phys*8
  const int swr = t >> 3, sp = t & 7;
  const __bf16* wsrc[4];
#pragma unroll
  for (int i = 0; i < 4; ++i)
    wsrc[i] = wt + (size_t)(oT * 128 + 32 * i + swr) * 4608 + sp * 8;

  // ---- halo staging: 8 chunks/thread over 6 rows x 42 cols x 8 c8-chunks
  const __bf16* inb = in + (size_t)n * (1156 * 512);
  const __bf16* hsrc[8];
  bool hval[8];
#pragma unroll
  for (int i = 0; i < 8; ++i) {
    const int jj = t + 256 * i;
    hval[i] = jj < 2016;
    const int hr = jj / 336;
    const int hrem = jj - hr * 336;
    const int hw = hrem >> 3, hc8 = hrem & 7;
    hsrc[i] = inb + ((size_t)((trow0 + hr) * 34 + hw)) * 512 +
              (hc8 ^ (hw & 7)) * 8;
  }

  // ---- fragment read constants
  const int c0 = (q ^ (l16 & 7)) * 8;
  const int c1 = ((4 + q) ^ (l16 & 7)) * 8;
  int aoff[4], prow_[4], pcol_[4];
#pragma unroll
  for (int i = 0; i < 4; ++i) {
    aoff[i] = (wrow * 64 + i * 16 + l16) * 64;
    const int p = wcol * 64 + i * 16 + l16;
    prow_[i] = p >> 5;
    pcol_[i] = p & 31;
  }

  f32x4 acc[4][4];
#pragma unroll
  for (int i = 0; i < 4; ++i)
#pragma unroll
    for (int j = 0; j < 4; ++j) acc[i][j] = (f32x4){0.f, 0.f, 0.f, 0.f};

  // ---- prologue: halo(cc=0), W(step0)->Wl[0], W(step1)->Wl[1] ------------
  // step s has (cc,tap) = (s/9, s%9); woffs = (tap*8+cc)*64.
#pragma unroll
  for (int i = 0; i < 8; ++i)
    if (hval[i]) GLDS16(hsrc[i], Hl + (t + 256 * i) * 8);
#pragma unroll
  for (int i = 0; i < 4; ++i)
    GLDS16(wsrc[i], Wl + (t + 256 * i) * 8);  // step0: woffs=0
#pragma unroll
  for (int i = 0; i < 4; ++i)
    GLDS16(wsrc[i] + 512, Wl + 8192 + (t + 256 * i) * 8);  // step1: woffs=512
  // outstanding: halo(8) + W0(4) + W1(4). Wait halo+W0; keep W1 in flight.
  asm volatile("s_waitcnt vmcnt(4)" ::: "memory");
  __builtin_amdgcn_s_barrier();

  int tap = 0, dh = 0, dw = 0, cc = 0;  // step s
  int tap2 = 2, cc2 = 0;                // step s+2 (prefetch target)

#pragma unroll 1
  for (int s = 0; s < 72; ++s) {
    const int buf = (s & 1) << 13;  // 0 or 8192 elements
    const __bf16* Wb = Wl + buf;

    // A: fragment reads for step s
    bf16x8 aw[4][2], bp[4][2];
#pragma unroll
    for (int i = 0; i < 4; ++i) {
      aw[i][0] = *(const bf16x8*)&Wb[aoff[i] + c0];
      aw[i][1] = *(const bf16x8*)&Wb[aoff[i] + c1];
    }
#pragma unroll
    for (int i = 0; i < 4; ++i) {
      const int col = pcol_[i] + dw;
      const int rb = (prow_[i] + dh) * 2688 + col * 64;
      const int xr = col & 7;
      bp[i][0] = *(const bf16x8*)&Hl[rb + (q ^ xr) * 8];
      bp[i][1] = *(const bf16x8*)&Hl[rb + ((4 + q) ^ xr) * 8];
    }
    // B/C: reads landed in regs (cross-wave WAR vs incoming DMA), then sync.
    asm volatile("s_waitcnt lgkmcnt(0)" ::: "memory");
    __builtin_amdgcn_sched_barrier(0);
    __builtin_amdgcn_s_barrier();

    // D: issue next-halo FIRST (FIFO: so vmcnt(4) below covers it), then
    //    W(s+2) into the buffer step s just finished reading.
    if (tap == 8 && cc < 7) {
#pragma unroll
      for (int i = 0; i < 8; ++i)
        if (hval[i]) GLDS16(hsrc[i] + (cc + 1) * 64, Hl + (t + 256 * i) * 8);
    }
    if (s < 70) {
      const int woffs2 = (tap2 * 8 + cc2) * 64;
#pragma unroll
      for (int i = 0; i < 4; ++i)
        GLDS16(wsrc[i] + woffs2, Wl + buf + (t + 256 * i) * 8);
    }

    // E: MFMA cluster (T5)
    __builtin_amdgcn_s_setprio(1);
#pragma unroll
    for (int kh = 0; kh < 2; ++kh)
#pragma unroll
      for (int mt = 0; mt < 4; ++mt)
#pragma unroll
        for (int nt = 0; nt < 4; ++nt)
          acc[mt][nt] = __builtin_amdgcn_mfma_f32_16x16x32_bf16(
              aw[mt][kh], bp[nt][kh], acc[mt][nt], 0, 0, 0);
    __builtin_amdgcn_s_setprio(0);

    // F/G: counted wait — drain {W(s+1), halo-if-issued}; W(s+2) stays in
    // flight across the barrier. Tail drains fully.
    if (s < 70)
      asm volatile("s_waitcnt vmcnt(4)" ::: "memory");
    else
      asm volatile("s_waitcnt vmcnt(0)" ::: "memory");
    __builtin_amdgcn_s_barrier();

    // advance step / prefetch counters
    ++tap;
    ++dw;
    if (dw == 3) {
      dw = 0;
      ++dh;
    }
    if (tap == 9) {
      tap = 0;
      dh = 0;
      dw = 0;
      ++cc;
    }
    if (++tap2 == 9) {
      tap2 = 0;
      ++cc2;
    }
  }

  // ---- epilogue ----
#pragma unroll
  for (int nt = 0; nt < 4; ++nt) {
    const int m_l = wcol * 64 + nt * 16 + l16;
    const int mg2 = bx * 128 + m_l;
    const int n2 = mg2 >> 10, pix2 = mg2 & 1023;
#pragma unroll
    for (int mt = 0; mt < 4; ++mt) {
      const int ob = oT * 128 + wrow * 64 + mt * 16 + q * 4;
      f32x4 v = acc[mt][nt];
      union {
        __bf16 b[4];
        uint2 u;
      } pk;
      if (MODE == 0) {
        const f32x4 sc = *(const f32x4*)&scale[ob];
        const f32x4 sh = *(const f32x4*)&shift[ob];
#pragma unroll
        for (int r = 0; r < 4; ++r)
          pk.b[r] = (__bf16)fmaxf(v[r] * sc[r] + sh[r], 0.f);
        __bf16* dst = outp +
                      ((size_t)n2 * 1156 + ((pix2 >> 5) + 1) * 34 +
                       ((pix2 & 31) + 1)) * 512 + ob;
        *(uint2*)dst = pk.u;
      } else {
#pragma unroll
        for (int r = 0; r < 4; ++r) pk.b[r] = (__bf16)v[r];
        __bf16* dst = outp + ((size_t)n2 * 1024 + pix2) * 512 + ob;
        *(uint2*)dst = pk.u;
      }
    }
  }
}

// ---------------- fused post-conv2: assign_softmax + expand_x --------------
// bx < 256: assign_softmax (latency-bound long pole — dispatched first),
//   8 iterations x 2 K-tiles: barriers halved vs 1-tile/iter.
// bx >= 256: expand_x (BW-bound, fills remaining CUs).
__global__ __launch_bounds__(256) void post_conv(
    const __bf16* __restrict__ xebT, const __bf16* __restrict__ watb,
    __bf16* __restrict__ saPb, float* __restrict__ S,
    float* __restrict__ xenc, __bf16* __restrict__ xeb) {
  __shared__ __align__(16) __bf16 Al[4][64 * 32];
  __shared__ __align__(16) __bf16 Wlb[4][64 * 32];
  __shared__ float Sl[64];
  const int t = threadIdx.x;
  const int bx0 = blockIdx.x;

  if (bx0 < 256) {
    // ======== assign_softmax (4-buffer, 2 tiles/iter) ========
    const int pt = bx0 & 15, n = bx0 >> 4;
    const int lane = t & 63, wid = t >> 6;
    const int l16 = lane & 15, q = lane >> 4;
    if (t < 64) Sl[t] = 0.f;

    const int arow = t >> 2;  // pixel row 0..63
    const __bf16* asrc = xebT + ((size_t)n * 1024 + pt * 64 + arow) * 512 +
                         ((t & 3) ^ ((arow >> 1) & 3)) * 8;
    const __bf16* wsrc = watb + (size_t)(t >> 2) * 512 + (t & 3) * 8;
    const int ldsb = wid * 512;
    const int sw = (q ^ ((l16 >> 1) & 3)) * 8;
    const int pnoff = (t >> 2) * 32 + (t & 3) * 8;

    f32x4 acc[4];
#pragma unroll
    for (int i = 0; i < 4; ++i) acc[i] = (f32x4){0.f, 0.f, 0.f, 0.f};
    float pn = 0.f;

    // prologue: issue tiles 0..3 (2 loads each, 8 total)
#pragma unroll
    for (int p = 0; p < 4; ++p) {
      GLDS16(asrc + p * 32, (__bf16*)Al[p] + ldsb);
      GLDS16(wsrc + p * 32, (__bf16*)Wlb[p] + ldsb);
    }
    asm volatile("s_waitcnt vmcnt(4)" ::: "memory");  // tiles 0,1 done
    __builtin_amdgcn_s_barrier();

#pragma unroll 1
    for (int J = 0; J < 8; ++J) {
      const int ka0 = 2 * J, kb0 = 2 * J + 1;
      const __bf16* Ab0 = Al[ka0 & 3];
      const __bf16* Wb0 = Wlb[ka0 & 3];
      const __bf16* Ab1 = Al[kb0 & 3];
      const __bf16* Wb1 = Wlb[kb0 & 3];
      // A: register reads of BOTH tiles
      bf16x8 pv0 = *(const bf16x8*)&Ab0[pnoff];
      bf16x8 pv1 = *(const bf16x8*)&Ab1[pnoff];
      bf16x8 pf0 = *(const bf16x8*)&Ab0[(wid * 16 + l16) * 32 + sw];
      bf16x8 pf1 = *(const bf16x8*)&Ab1[(wid * 16 + l16) * 32 + sw];
      bf16x8 wf0[4], wf1[4];
#pragma unroll
      for (int ka = 0; ka < 4; ++ka) {
        wf0[ka] = *(const bf16x8*)&Wb0[(ka * 16 + l16) * 32 + sw];
        wf1[ka] = *(const bf16x8*)&Wb1[(ka * 16 + l16) * 32 + sw];
      }
      // B: all waves' reads landed before buffer reuse
      asm volatile("s_waitcnt lgkmcnt(0)" ::: "memory");
      __builtin_amdgcn_sched_barrier(0);
      __builtin_amdgcn_s_barrier();
      // C: issue tiles 2J+4, 2J+5 into the two buffers just freed
      if (J < 6) {
        GLDS16(asrc + (2 * J + 4) * 32, (__bf16*)Al[ka0 & 3] + ldsb);
        GLDS16(wsrc + (2 * J + 4) * 32, (__bf16*)Wlb[ka0 & 3] + ldsb);
        GLDS16(asrc + (2 * J + 5) * 32, (__bf16*)Al[kb0 & 3] + ldsb);
        GLDS16(wsrc + (2 * J + 5) * 32, (__bf16*)Wlb[kb0 & 3] + ldsb);
      }
      // D: compute both tiles
#pragma unroll
      for (int j = 0; j < 8; ++j) {
        float f0 = (float)pv0[j];
        pn = fmaf(f0, f0, pn);
        float f1 = (float)pv1[j];
        pn = fmaf(f1, f1, pn);
      }
#pragma unroll
      for (int ka = 0; ka < 4; ++ka) {
        acc[ka] = __builtin_amdgcn_mfma_f32_16x16x32_bf16(wf0[ka], pf0,
                                                          acc[ka], 0, 0, 0);
        acc[ka] = __builtin_amdgcn_mfma_f32_16x16x32_bf16(wf1[ka], pf1,
                                                          acc[ka], 0, 0, 0);
      }
      // E/F: counted wait — tiles 2J+2,2J+3 ready; 2J+4,2J+5 stay in flight
      if (J < 6)
        asm volatile("s_waitcnt vmcnt(4)" ::: "memory");
      else
        asm volatile("s_waitcnt vmcnt(0)" ::: "memory");
      __builtin_amdgcn_s_barrier();
    }
    pn += __shfl_xor(pn, 1);
    pn += __shfl_xor(pn, 2);
    const float rn = 1.0f / fmaxf(sqrtf(__shfl(pn, l16 * 4)), 1e-12f);

    float sc[16];
    float m = -3.4e38f;
#pragma unroll
    for (int ka = 0; ka < 4; ++ka)
#pragma unroll
      for (int r = 0; r < 4; ++r) {
        float v = acc[ka][r] * rn;
        sc[ka * 4 + r] = v;
        m = fmaxf(m, v);
      }
    m = fmaxf(m, __shfl_xor(m, 16));
    m = fmaxf(m, __shfl_xor(m, 32));
    float s = 0.f;
#pragma unroll
    for (int j = 0; j < 16; ++j) {
      sc[j] = __expf(sc[j] - m);
      s += sc[j];
    }
    s += __shfl_xor(s, 16);
    s += __shfl_xor(s, 32);
    const float inv = 1.0f / s;
    const int pixg = pt * 64 + wid * 16 + l16;
#pragma unroll
    for (int j = 0; j < 16; ++j) {
      const int k = (j >> 2) * 16 + q * 4 + (j & 3);
      float sa = sc[j] * inv;
      sc[j] = sa;
      saPb[((size_t)n * 64 + k) * 1024 + pixg] = (__bf16)(sa * rn);
    }
#pragma unroll
    for (int j = 0; j < 16; ++j) {
      float v = sc[j];
      v += __shfl_xor(v, 1);
      v += __shfl_xor(v, 2);
      v += __shfl_xor(v, 4);
      v += __shfl_xor(v, 8);
      sc[j] = v;
    }
    if (l16 == 0) {
#pragma unroll
      for (int j = 0; j < 16; ++j)
        atomicAdd(&Sl[(j >> 2) * 16 + q * 4 + (j & 3)], sc[j]);
    }
    __syncthreads();
    if (t < 64) atomicAdd(&S[n * 64 + t], Sl[t]);
  } else {
    // ======== expand_x: xebT [pix][c] -> xenc fp32 [c][pix] + xeb bf16 ====
    const int e = bx0 - 256;
    const int cc = e & 7, ptile = (e >> 3) & 15, n = e >> 7;
    __bf16* Ll = (__bf16*)Al;  // 8 KB carve
    const int p0 = ptile * 64, c0 = cc * 64;
#pragma unroll
    for (int i = 0; i < 2; ++i) {
      const int u = t * 2 + i;
      const int pix = u >> 3, c8 = u & 7;
      uint4 v = *(const uint4*)&xebT[((size_t)n * 1024 + p0 + pix) * 512 + c0 +
                                     c8 * 8];
      *(uint4*)&Ll[pix * 64 + (c8 ^ (pix & 7)) * 8] = v;
    }
    __syncthreads();
    const int c = t >> 2, g = t & 3;
    union {
      float f[4];
      float4 v;
    } fv[4];
    union {
      __bf16 b[16];
      uint4 u[2];
    } bv;
#pragma unroll
    for (int r = 0; r < 16; ++r) {
      const int pix = g * 16 + r;
      __bf16 b = Ll[pix * 64 + ((c >> 3) ^ (pix & 7)) * 8 + (c & 7)];
      bv.b[r] = b;
      fv[r >> 2].f[r & 3] = (float)b;
    }
    float* fd = xenc + ((size_t)n * 512 + c0 + c) * 1024 + p0 + g * 16;
#pragma unroll
    for (int r = 0; r < 4; ++r) *(float4*)(fd + r * 4) = fv[r].v;
    __bf16* bd = xeb + ((size_t)n * 512 + c0 + c) * 1024 + p0 + g * 16;
    *(uint4*)bd = bv.u[0];
    *(uint4*)(bd + 8) = bv.u[1];
  }
}

// ---------------- VLAD aggregation: bf16 MFMA GEMM (2 tiles/iter) ----------
__global__ __launch_bounds__(256) void vlad_gemm(
    const __bf16* __restrict__ saPb, const __bf16* __restrict__ xeb,
    float* __restrict__ vpart) {
  __shared__ __align__(16) __bf16 Al[4][64 * 32];
  __shared__ __align__(16) __bf16 Bl[4][128 * 32];

  const int t = threadIdx.x;
  const int cT = blockIdx.x, n = blockIdx.y, ks = blockIdx.z;
  const int lane = t & 63, wid = t >> 6;
  const int l16 = lane & 15, q = lane >> 4;
  const int wrow = wid >> 1, wcol = wid & 1;

  const int ar = t >> 2, acp = t & 3;
  const __bf16* asrc = saPb + (size_t)n * 65536 + (size_t)ar * 1024 + ks * 256 +
                       (acp ^ ((ar >> 1) & 3)) * 8;
  const int br0 = t >> 2, bcp0 = t & 3;
  const int br1 = (t + 256) >> 2, bcp1 = t & 3;
  const __bf16* bsrc0 = xeb + (size_t)n * 524288 +
                        (size_t)(cT * 128 + br0) * 1024 + ks * 256 +
                        (bcp0 ^ ((br0 >> 1) & 3)) * 8;
  const __bf16* bsrc1 = xeb + (size_t)n * 524288 +
                        (size_t)(cT * 128 + br1) * 1024 + ks * 256 +
                        (bcp1 ^ ((br1 >> 1) & 3)) * 8;

  const int ldsb = wid * 512;
  const int sw = (q ^ ((l16 >> 1) & 3)) * 8;

  f32x4 acc[2][4];
#pragma unroll
  for (int i = 0; i < 2; ++i)
#pragma unroll
    for (int j = 0; j < 4; ++j) acc[i][j] = (f32x4){0.f, 0.f, 0.f, 0.f};

  // prologue: issue tiles 0..3 (3 loads each, 12 total)
#pragma unroll
  for (int p = 0; p < 4; ++p) {
    GLDS16(asrc + p * 32, (__bf16*)Al[p] + ldsb);
    GLDS16(bsrc0 + p * 32, (__bf16*)Bl[p] + ldsb);
    GLDS16(bsrc1 + p * 32, (__bf16*)Bl[p] + 2048 + ldsb);
  }
  asm volatile("s_waitcnt vmcnt(6)" ::: "memory");  // tiles 0,1 done
  __builtin_amdgcn_s_barrier();

#pragma unroll 1
  for (int J = 0; J < 4; ++J) {
    const int ka0 = 2 * J, kb0 = 2 * J + 1;
    const __bf16* Ab0 = Al[ka0 & 3];
    const __bf16* Bb0 = Bl[ka0 & 3];
    const __bf16* Ab1 = Al[kb0 & 3];
    const __bf16* Bb1 = Bl[kb0 & 3];
    // A: register reads of BOTH tiles
    bf16x8 af0[2], bf0[4], af1[2], bf1[4];
#pragma unroll
    for (int i = 0; i < 2; ++i) {
      af0[i] = *(const bf16x8*)&Ab0[(wrow * 32 + i * 16 + l16) * 32 + sw];
      af1[i] = *(const bf16x8*)&Ab1[(wrow * 32 + i * 16 + l16) * 32 + sw];
    }
#pragma unroll
    for (int i = 0; i < 4; ++i) {
      bf0[i] = *(const bf16x8*)&Bb0[(wcol * 64 + i * 16 + l16) * 32 + sw];
      bf1[i] = *(const bf16x8*)&Bb1[(wcol * 64 + i * 16 + l16) * 32 + sw];
    }
    // B: reads landed before buffer reuse
    asm volatile("s_waitcnt lgkmcnt(0)" ::: "memory");
    __builtin_amdgcn_sched_barrier(0);
    __builtin_amdgcn_s_barrier();
    // C: issue tiles 2J+4, 2J+5
    if (J < 2) {
      GLDS16(asrc + (2 * J + 4) * 32, (__bf16*)Al[ka0 & 3] + ldsb);
      GLDS16(bsrc0 + (2 * J + 4) * 32, (__bf16*)Bl[ka0 & 3] + ldsb);
      GLDS16(bsrc1 + (2 * J + 4) * 32, (__bf16*)Bl[ka0 & 3] + 2048 + ldsb);
      GLDS16(asrc + (2 * J + 5) * 32, (__bf16*)Al[kb0 & 3] + ldsb);
      GLDS16(bsrc0 + (2 * J + 5) * 32, (__bf16*)Bl[kb0 & 3] + ldsb);
      GLDS16(bsrc1 + (2 * J + 5) * 32, (__bf16*)Bl[kb0 & 3] + 2048 + ldsb);
    }
    // D: MFMA both tiles
#pragma unroll
    for (int mt = 0; mt < 2; ++mt)
#pragma unroll
      for (int nt = 0; nt < 4; ++nt) {
        acc[mt][nt] = __builtin_amdgcn_mfma_f32_16x16x32_bf16(
            af0[mt], bf0[nt], acc[mt][nt], 0, 0, 0);
        acc[mt][nt] = __builtin_amdgcn_mfma_f32_16x16x32_bf16(
            af1[mt], bf1[nt], acc[mt][nt], 0, 0, 0);
      }
    // E/F: counted wait — tiles 2J+2,2J+3 ready; 2J+4,2J+5 stay in flight
    if (J < 2)
      asm volatile("s_waitcnt vmcnt(6)" ::: "memory");
    else
      asm volatile("s_waitcnt vmcnt(0)" ::: "memory");
    __builtin_amdgcn_s_barrier();
  }

  float* vp = vpart + (size_t)(ks * 16 + n) * 32768;
#pragma unroll
  for (int mt = 0; mt < 2; ++mt) {
    const int krow = wrow * 32 + mt * 16 + q * 4;
#pragma unroll
    for (int nt = 0; nt < 4; ++nt) {
      const int ccol = cT * 128 + wcol * 64 + nt * 16 + l16;
#pragma unroll
      for (int r = 0; r < 4; ++r)
        vp[(size_t)(krow + r) * 512 + ccol] = acc[mt][nt][r];
    }
  }
}

// ---------------- fused intra-norm + global-norm + finalize ----------------
// one block per image n: 16 blocks x 1024 threads (16 waves). Wave w handles
// rows k = w*4 .. w*4+3 (8 values/lane each, kept in registers). gss reduced
// in LDS across the block's waves; out written directly with float4 stores.
__global__ __launch_bounds__(1024) void norm_out(
    const float* __restrict__ vpart, const float* __restrict__ S,
    const float* __restrict__ cent, float* __restrict__ out) {
  __shared__ float Gs[16];
  const int n = blockIdx.x;  // 0..15
  const int t = threadIdx.x;
  const int wid = t >> 6, lane = t & 63;

  float vv[4][8];
  float rns[4];
  float gs = 0.f;
#pragma unroll
  for (int rr = 0; rr < 4; ++rr) {
    const int k = wid * 4 + rr;
    const int b = n * 64 + k;
    const float s = S[b];
    float ss = 0.f;
#pragma unroll
    for (int j = 0; j < 8; ++j) {
      const int c = lane * 8 + j;
      const size_t off = (size_t)b * 512 + c;
      float val = vpart[off] + vpart[524288 + off] + vpart[2 * 524288 + off] +
                  vpart[3 * 524288 + off] - s * cent[k * 512 + c];
      vv[rr][j] = val;
      ss += val * val;
    }
#pragma unroll
    for (int off = 1; off < 64; off <<= 1) ss += __shfl_xor(ss, off);
    const float rn = 1.0f / fmaxf(sqrtf(ss), 1e-12f);
    rns[rr] = rn;
    gs += ss * rn * rn;  // same on all lanes of the wave
  }
  if (lane == 0) Gs[wid] = gs;
  __syncthreads();
  float g = 0.f;
#pragma unroll
  for (int i = 0; i < 16; ++i) g += Gs[i];
  const float gr = 1.0f / fmaxf(sqrtf(g), 1e-12f);

#pragma unroll
  for (int rr = 0; rr < 4; ++rr) {
    const int k = wid * 4 + rr;
    const float f = rns[rr] * gr;
    float* dst = out + ((size_t)(n * 64 + k)) * 512 + lane * 8;
    float4 a = {vv[rr][0] * f, vv[rr][1] * f, vv[rr][2] * f, vv[rr][3] * f};
    float4 b4 = {vv[rr][4] * f, vv[rr][5] * f, vv[rr][6] * f, vv[rr][7] * f};
    *(float4*)dst = a;
    *(float4*)(dst + 4) = b4;
  }
}

// ---------------- fused prep: zero_border + misc + xform + wt_prep ---------
// grid layout: [0,1056) zero-border, [1056,1191) misc, [1191,1703) xform,
// [1703,2727) wt_prep. All independent writes; fusing overlaps them across
// CUs and drops 3 launch gaps.
__global__ __launch_bounds__(256) void prep_all(
    const float* __restrict__ x, const float* __restrict__ w1,
    const float* __restrict__ w2, const float* __restrict__ g,
    const float* __restrict__ b, const float* __restrict__ m,
    const float* __restrict__ v, const float* __restrict__ wA,
    __bf16* __restrict__ xpad, __bf16* __restrict__ hpad,
    __bf16* __restrict__ wt1, __bf16* __restrict__ wt2,
    float* __restrict__ scale, float* __restrict__ shift,
    __bf16* __restrict__ watb, float* __restrict__ Sz) {
  __shared__ float Lw[4608];
  const int bx = blockIdx.x;
  const int t = threadIdx.x;

  if (bx < 1056) {
    // ---- zero the 132-pixel pad ring of xpad/hpad ----
    const int which = bx >= 528;
    const int id = (which ? bx - 528 : bx) * 256 + t;  // 0..135167
    const int n = id / 8448;
    const int rem = id - n * 8448;
    const int pb = rem >> 6;  // 0..131 border pixel
    const int c8 = rem & 63;
    int h, w;
    if (pb < 34) {
      h = 0;
      w = pb;
    } else if (pb < 68) {
      h = 33;
      w = pb - 34;
    } else {
      const int r2 = pb - 68;
      h = 1 + (r2 >> 1);
      w = (r2 & 1) * 33;
    }
    __bf16* base = which ? hpad : xpad;
    *(uint4*)(base + ((size_t)n * 1156 + h * 34 + w) * 512 + c8 * 8) =
        (uint4){0u, 0u, 0u, 0u};
  } else if (bx < 1191) {
    // ---- misc: BN fold, watb swizzle, S zero ----
    const int i = (bx - 1056) * 256 + t;
    if (i < 512) {
      float sc = g[i] / sqrtf(v[i] + 1e-5f);
      scale[i] = sc;
      shift[i] = b[i] - m[i] * sc;
    } else if (i < 512 + 32768) {
      const int id = i - 512;
      const int k = id >> 9, j = id & 511;
      const int kt = j >> 5, cpos = (j >> 3) & 3, e = j & 7;
      const int c = kt * 32 + (cpos ^ ((k >> 1) & 3)) * 8 + e;
      watb[(size_t)k * 512 + j] = (__bf16)wA[(size_t)k * 512 + c];
    } else if (i < 512 + 32768 + 1040) {
      Sz[i - (512 + 32768)] = 0.f;
    }
  } else if (bx < 1703) {
    // ---- xform: x (fp32 NCHW) -> xpad (bf16 NHWC padded) ----
    const int bb = bx - 1191;
    const int n = bb >> 5, h = bb & 31;
    const int w = t & 31, cg = t >> 5;
    const float* src = x + ((size_t)n * 512 + cg * 64) * 1024 + h * 32 + w;
    __bf16* dst =
        xpad + ((size_t)n * 1156 + (h + 1) * 34 + (w + 1)) * 512 + cg * 64;
    float fv[64];
#pragma unroll
    for (int j = 0; j < 64; ++j) fv[j] = src[j * 1024];  // all loads in flight
#pragma unroll
    for (int jj = 0; jj < 8; ++jj) {
      union {
        __bf16 b8[8];
        uint4 u;
      } pk;
#pragma unroll
      for (int j = 0; j < 8; ++j) pk.b8[j] = (__bf16)fv[jj * 8 + j];
      *(uint4*)(dst + jj * 8) = pk.u;
    }
  } else {
    // ---- wt_prep: OIHW fp32 -> [o][kt*64 + p*8 + e] bf16, swizzle baked ---
    const int bb = bx - 1703;  // 0..1023
    const int o = bb & 511;
    const float* w = (bb >> 9) ? w2 : w1;
    __bf16* wt = (bb >> 9) ? wt2 : wt1;
#pragma unroll
    for (int i = 0; i < 18; ++i)
      Lw[t + 256 * i] = w[(size_t)o * 4608 + t + 256 * i];
    __syncthreads();
#pragma unroll
    for (int i = 0; i < 18; ++i) {
      const int idk = t + 256 * i;
      const int kt = idk >> 6;
      const int p = (idk >> 3) & 7, e = idk & 7;
      const int logical = p ^ (o & 7);
      const int k2 = kt * 64 + logical * 8 + e;
      const int tap = k2 >> 9, ci = k2 & 511;
      wt[(size_t)o * 4608 + idk] = (__bf16)Lw[ci * 9 + tap];
    }
  }
}

// ---------------------------------------------------------------------------
extern "C" void kernel_launch(void* const* d_in, const int* in_sizes, int n_in,
                              void* d_out, int out_size, void* d_ws,
                              size_t ws_size, hipStream_t stream) {
  const float* x = (const float*)d_in[0];
  const float* w1 = (const float*)d_in[1];
  const float* gam = (const float*)d_in[2];
  const float* bet = (const float*)d_in[3];
  const float* mean = (const float*)d_in[4];
  const float* var = (const float*)d_in[5];
  const float* w2 = (const float*)d_in[6];
  const float* wA = (const float*)d_in[7];
  const float* cent = (const float*)d_in[8];
  float* out = (float*)d_out;

  char* ws = (char*)d_ws;
  __bf16* Wt1 = (__bf16*)(ws + 0);          // 4,718,592 (dead after conv1)
  __bf16* Wt2 = (__bf16*)(ws + 4718592);    // 4,718,592 (dead after conv2)
  __bf16* xpad = (__bf16*)(ws + 9437184);   // 18,939,904 (dead after conv1)
  __bf16* xebT = (__bf16*)(ws + 9437184);   // alias: 16,777,216 (conv2 out)
  __bf16* saPb = (__bf16*)(ws + 26214400);  // 2,097,152
  __bf16* hpad = (__bf16*)(ws + 28377088);  // 18,939,904 (dead after conv2)
  __bf16* xeb = (__bf16*)(ws + 28377088);   // alias: 16,777,216 (expand out)
  float* vpart = (float*)(ws + 0);          // alias Wt1/2: 8,388,608
  float* scale = (float*)(ws + 47316992);   // 2048 B
  float* shift = (float*)(ws + 47319040);   // 2048 B
  __bf16* watb = (__bf16*)(ws + 47321088);  // 65,536 B
  float* S = (float*)(ws + 47386624);       // 4096 B

  float* xenc = out + 524288;  // output 1 (x_enc, fp32 NCHW)

  prep_all<<<2727, 256, 0, stream>>>(x, w1, w2, gam, bet, mean, var, wA, xpad,
                                     hpad, Wt1, Wt2, scale, shift, watb, S);

  conv_gemm<0><<<dim3(128, 4), 256, 0, stream>>>(xpad, Wt1, scale, shift, hpad);
  conv_gemm<1><<<dim3(128, 4), 256, 0, stream>>>(hpad, Wt2, nullptr, nullptr,
                                                 xebT);

  post_conv<<<2304, 256, 0, stream>>>(xebT, watb, saPb, S, xenc, xeb);
  vlad_gemm<<<dim3(4, 16, 4), 256, 0, stream>>>(saPb, xeb, vpart);
  norm_out<<<16, 1024, 0, stream>>>(vpart, S, cent, out);
}